// Round 10
// baseline (522.369 us; speedup 1.0000x reference)
//
#include <hip/hip_runtime.h>
#include <cstdint>
#include <cstddef>

#define NN 10000
#define NE 160000
#define ET (NE + NN)          // edges + self loops
#define FIN 2000
#define MPAD 10112            // 158 * 64 = 79 * 128
#define KPAD 2048
#define NPAD 896              // 7 * 128 (768 gat1 cols + 64 skip + 64 pad)

typedef __bf16 bf16x8 __attribute__((ext_vector_type(8)));
typedef __bf16 bf16x4 __attribute__((ext_vector_type(4)));
typedef float  f32x4  __attribute__((ext_vector_type(4)));

#define GLL(src, dst) __builtin_amdgcn_global_load_lds( \
    (const __attribute__((address_space(1))) void*)(src), \
    (__attribute__((address_space(3))) void*)(dst), 16, 0, 0)

// ---------------------------------------------------------------------------
// CSR build
// ---------------------------------------------------------------------------
__device__ __forceinline__ void edge_sd(const int* ei, int e, int& s, int& d) {
    if (e < NE) { s = ei[e]; d = ei[NE + e]; }
    else        { s = e - NE; d = e - NE; }
}

__global__ void count_kernel(const int* ei, int* deg) {
    int e = blockIdx.x * blockDim.x + threadIdx.x;
    if (e >= ET) return;
    int s, d; edge_sd(ei, e, s, d);
    atomicAdd(&deg[d], 1);
}

// exclusive scan over deg -> rowstart[0..NN]; also dinv = deg^-1/2
__global__ void scan_kernel(const int* deg, int* rowstart, float* dinv) {
    __shared__ int partial[256];
    const int T = 256;
    int chunk = (NN + T - 1) / T;
    int t = threadIdx.x;
    int begin = t * chunk;
    int end = begin + chunk; if (end > NN) end = NN;
    int s = 0;
    for (int i = begin; i < end && i >= begin; i++) s += deg[i];
    partial[t] = s;
    __syncthreads();
    if (t == 0) {
        int run = 0;
        for (int i = 0; i < T; i++) { int v = partial[i]; partial[i] = run; run += v; }
    }
    __syncthreads();
    int run = partial[t];
    for (int i = begin; i < end && i >= begin; i++) {
        rowstart[i] = run; run += deg[i];
        int dg = deg[i];
        dinv[i] = dg > 0 ? rsqrtf((float)dg) : 0.f;
    }
    if (end == NN && begin <= NN) rowstart[NN] = run;
}

__global__ void scatter_kernel(const int* ei, const int* rowstart, int* cursor,
                               int* csr_src) {
    int e = blockIdx.x * blockDim.x + threadIdx.x;
    if (e >= ET) return;
    int s, d; edge_sd(ei, e, s, d);
    int pos = atomicAdd(&cursor[d], 1);
    csr_src[rowstart[d] + pos] = s;
}

// ---------------------------------------------------------------------------
// Merged swizzled bf16 conversion.
// xb chunk c = ((rt*32 + ks)*8 + p)*64 + r holds x[rt*64+r][ks*64+p*8 ..+8)
// Blocks 0..5055: one (rt,ks) slab via LDS (coalesced read AND write).
// Blocks 5056.. : wt / w2t conversion (flat, per-thread).
// wt chunk: ((ct*32 + ks)*8 + p)*128 + r ; w2t chunk: (ct*16 + p)*128 + r
// ---------------------------------------------------------------------------
#define NBX (158 * 32)
#define NW1 (NPAD * KPAD / 8)
__global__ void conv_kernel(const float* __restrict__ x, __bf16* __restrict__ xb,
                            const float* __restrict__ Wg, const float* __restrict__ Ws,
                            const float* __restrict__ W2,
                            __bf16* __restrict__ wt, __bf16* __restrict__ w2t) {
    __shared__ __bf16 slab[4096];   // 8 planes x 64 rows x 8 = output chunk layout
    int bid = blockIdx.x;
    int tid = threadIdx.x;
    if (bid < NBX) {
        int rt = bid >> 5, ks = bid & 31;
        int r = tid >> 2;                 // 0..63
        int row = rt * 64 + r;
        int c0 = (tid & 3) * 16;          // 0,16,32,48
        int kbase = ks * 64;
#pragma unroll
        for (int j = 0; j < 4; j++) {
            int kl = c0 + j * 4;          // local k, mult of 4
            int k = kbase + kl;
            bf16x4 o;
            if (row < NN && k + 3 < FIN) {
                float4 v = *(const float4*)(x + (size_t)row * FIN + k);
                o[0] = (__bf16)v.x; o[1] = (__bf16)v.y;
                o[2] = (__bf16)v.z; o[3] = (__bf16)v.w;
            } else {
                o[0] = o[1] = o[2] = o[3] = (__bf16)0.f;
            }
            int p = kl >> 3, off = kl & 7;
            *(bf16x4*)(slab + (p * 64 + r) * 8 + off) = o;
        }
        __syncthreads();
        size_t base = (size_t)(rt * 32 + ks) * 512;   // chunk index
#pragma unroll
        for (int i = 0; i < 2; i++) {
            int c = i * 256 + tid;
            *(bf16x8*)(xb + (base + c) * 8) = *(const bf16x8*)(slab + c * 8);
        }
    } else {
        int g = (bid - NBX) * 256 + tid;
        if (g < NW1) {
            int r = g & 127, p = (g >> 7) & 7, ks = (g >> 10) & 31, ct = g >> 15;
            int n = ct * 128 + r;
            int k0 = ks * 64 + p * 8;
            bf16x8 o;
#pragma unroll
            for (int j = 0; j < 8; j++) {
                int k = k0 + j;
                float v = 0.f;
                if (k < FIN) {
                    if (n < 768)      v = Wg[(size_t)k * 768 + n];
                    else if (n < 832) v = Ws[(size_t)k * 64 + (n - 768)];
                }
                o[j] = (__bf16)v;
            }
            *(bf16x8*)(wt + (size_t)g * 8) = o;
        } else if (g < NW1 + 512 * 128 / 8) {
            int g2 = g - NW1;
            int c = g2 & 2047;
            int ct = g2 >> 11;
            int p = c >> 7, r = c & 127;
            int n = ct * 128 + r;
            int k0 = p * 8;
            bf16x8 o;
#pragma unroll
            for (int j = 0; j < 8; j++)
                o[j] = (__bf16)W2[(size_t)(k0 + j) * 512 + n];
            *(bf16x8*)(w2t + (size_t)g2 * 8) = o;
        }
    }
}

// ---------------------------------------------------------------------------
// MFMA GEMM 1: xb @ wt^T -> h1b bf16[NN,768], skippre f32[NN,64], + fused
// alpha1. 128M x 128N block, 4 waves of 64x64 each (2x2), BK=64, 256 thr.
// 64x64 wave tile halves LDS reads per MFMA vs 32x64 (perimeter/area).
// ---------------------------------------------------------------------------
__global__ __launch_bounds__(256)
void mfma_gemm1_kernel(const __bf16* __restrict__ xb, const __bf16* __restrict__ wt,
                       const float* __restrict__ a_src1, const float* __restrict__ a_dst1,
                       __bf16* __restrict__ h1b, float* __restrict__ skippre,
                       float* __restrict__ asrc, float* __restrict__ adst) {
    __shared__ __bf16 As[8192];    // 8 planes x 128 rows x 8 (16 KB)
    __shared__ __bf16 Bs[8192];    // 8 planes x 128 rows x 8 (16 KB)
    __shared__ float sA[128], sD[128];
    __shared__ float asd[256];
    int b = blockIdx.x;
    int xcd = b & 7, j = b >> 3;          // j 0..69
    int jq = j / 7;                        // 0..9
    int rt = xcd + 8 * jq;                 // 0..79 (128-row tiles)
    int ct = j - 7 * jq;                   // 0..6
    if (rt >= MPAD / 128) return;
    const int bi = rt * 128;
    const int bn = ct * 128;

    const int tid = threadIdx.x;
    const int lane = tid & 63;
    const int w = tid >> 6;                // 0..3
    const int wm = w >> 1, wn = w & 1;
    const int q = lane >> 4, m16 = lane & 15;

    if (tid < 128) { sA[tid] = 0.f; sD[tid] = 0.f; }
    if (ct < 6) {
        if (tid < 128) asd[tid] = a_src1[ct * 128 + tid];
        else           asd[tid] = a_dst1[ct * 128 + (tid - 128)];
    }

    f32x4 acc[4][4] = {};

    for (int ks = 0; ks < KPAD / 64; ks++) {
        // A: two 64-row slabs (rt*2, rt*2+1) -> As[plane][128 rows][8]
        const size_t slabA0 = (size_t)((2 * rt) * 32 + ks) * 512;
        const size_t slabA1 = (size_t)((2 * rt + 1) * 32 + ks) * 512;
        const size_t slabB  = (size_t)(ct * 32 + ks) * 1024;
#pragma unroll
        for (int i = 0; i < 4; i++) {
            int gi = i * 4 + w;            // 0..15
            int half = gi >> 3, pl = gi & 7;
            const __bf16* src = xb + ((half ? slabA1 : slabA0) + (size_t)pl * 64 + lane) * 8;
            GLL(src, As + (pl * 128 + half * 64) * 8);
        }
#pragma unroll
        for (int i = 0; i < 4; i++) {
            int seg = i * 4 + w;           // 0..15, 64 chunks each
            GLL(wt + (slabB + seg * 64 + lane) * 8, Bs + seg * 512);
        }
        __syncthreads();

#pragma unroll
        for (int kk = 0; kk < 2; kk++) {
            const int pb = kk * 4 + q;
            bf16x8 af[4], bfr[4];
#pragma unroll
            for (int mt = 0; mt < 4; mt++)
                af[mt] = *(const bf16x8*)(As + (pb * 128 + wm * 64 + mt * 16 + m16) * 8);
#pragma unroll
            for (int nt = 0; nt < 4; nt++)
                bfr[nt] = *(const bf16x8*)(Bs + (pb * 128 + wn * 64 + nt * 16 + m16) * 8);
#pragma unroll
            for (int mt = 0; mt < 4; mt++)
#pragma unroll
                for (int nt = 0; nt < 4; nt++)
                    acc[mt][nt] = __builtin_amdgcn_mfma_f32_16x16x32_bf16(af[mt], bfr[nt], acc[mt][nt], 0, 0, 0);
        }
        __syncthreads();
    }

    // epilogue: stores + fused alpha. row=bi+wm*64+mt*16+q*4+r, col=bn+wn*64+nt*16+m16
#pragma unroll
    for (int mt = 0; mt < 4; mt++) {
#pragma unroll
        for (int r = 0; r < 4; r++) {
            int rowl = wm * 64 + mt * 16 + q * 4 + r;
            int row = bi + rowl;
            float ps = 0.f, pd = 0.f;
#pragma unroll
            for (int nt = 0; nt < 4; nt++) {
                int coll = wn * 64 + nt * 16 + m16;
                int col = bn + coll;
                float v = acc[mt][nt][r];
                if (ct < 6) { ps += v * asd[coll]; pd += v * asd[128 + coll]; }
                if (row < NN) {
                    if (col < 768)      h1b[(size_t)row * 768 + col] = (__bf16)v;
                    else if (col < 832) skippre[(size_t)row * 64 + (col - 768)] = v;
                }
            }
            if (ct < 6) {
#pragma unroll
                for (int off = 1; off < 16; off <<= 1) {
                    ps += __shfl_xor(ps, off);
                    pd += __shfl_xor(pd, off);
                }
                if (m16 == 0) { atomicAdd(&sA[rowl], ps); atomicAdd(&sD[rowl], pd); }
            }
        }
    }
    if (ct < 6) {
        __syncthreads();
        if (tid < 128) {
            int row = bi + tid;
            if (row < NN) { asrc[row * 6 + ct] = sA[tid]; adst[row * 6 + ct] = sD[tid]; }
        }
    }
}

// ---------------------------------------------------------------------------
// MFMA GEMM 2: x1gcnb(swizzled)[MPAD,128] @ w2t(swizzled)[512,128]^T -> h2b
// bf16[NN,512], + fused alpha2. 64x128 block, 4 waves (32x64), BK=64, 256 thr.
// ---------------------------------------------------------------------------
__global__ __launch_bounds__(256)
void mfma_gemm2_kernel(const __bf16* __restrict__ A, const __bf16* __restrict__ B,
                       const float* __restrict__ a_src2, const float* __restrict__ a_dst2,
                       __bf16* __restrict__ h2b,
                       float* __restrict__ asrc, float* __restrict__ adst) {
    __shared__ __bf16 As[4096];
    __shared__ __bf16 Bs[8192];
    __shared__ float sA[64], sD[64];
    __shared__ float asd[256];
    const int rt = blockIdx.y, ct = blockIdx.x;
    const int bi = rt * 64, bn = ct * 128;
    const int tid = threadIdx.x, lane = tid & 63, w = tid >> 6;
    const int wm = w >> 1, wn = w & 1;
    const int q = lane >> 4, m16 = lane & 15;

    if (tid < 64) { sA[tid] = 0.f; sD[tid] = 0.f; }
    if (tid < 128) asd[tid] = a_src2[ct * 128 + tid];
    else           asd[tid] = a_dst2[ct * 128 + (tid - 128)];

    f32x4 acc[2][4] = {};

    for (int ks = 0; ks < 2; ks++) {
        const size_t slabA = (size_t)rt * 1024 + ks * 512;
        const size_t slabB = (size_t)ct * 2048 + ks * 1024;
#pragma unroll
        for (int i = 0; i < 2; i++) {
            int seg = i * 4 + w;
            GLL(A + (slabA + seg * 64 + lane) * 8, As + seg * 512);
        }
#pragma unroll
        for (int i = 0; i < 4; i++) {
            int seg = i * 4 + w;
            GLL(B + (slabB + seg * 64 + lane) * 8, Bs + seg * 512);
        }
        __syncthreads();

#pragma unroll
        for (int kk = 0; kk < 2; kk++) {
            const int pb = kk * 4 + q;
            bf16x8 af[2], bfr[4];
#pragma unroll
            for (int mt = 0; mt < 2; mt++)
                af[mt] = *(const bf16x8*)(As + (pb * 64 + wm * 32 + mt * 16 + m16) * 8);
#pragma unroll
            for (int nt = 0; nt < 4; nt++)
                bfr[nt] = *(const bf16x8*)(Bs + (pb * 128 + wn * 64 + nt * 16 + m16) * 8);
#pragma unroll
            for (int mt = 0; mt < 2; mt++)
#pragma unroll
                for (int nt = 0; nt < 4; nt++)
                    acc[mt][nt] = __builtin_amdgcn_mfma_f32_16x16x32_bf16(af[mt], bfr[nt], acc[mt][nt], 0, 0, 0);
        }
        __syncthreads();
    }

#pragma unroll
    for (int mt = 0; mt < 2; mt++) {
#pragma unroll
        for (int r = 0; r < 4; r++) {
            int rowl = wm * 32 + mt * 16 + q * 4 + r;
            int row = bi + rowl;
            float ps = 0.f, pd = 0.f;
#pragma unroll
            for (int nt = 0; nt < 4; nt++) {
                int coll = wn * 64 + nt * 16 + m16;
                float v = acc[mt][nt][r];
                ps += v * asd[coll]; pd += v * asd[128 + coll];
                if (row < NN) h2b[(size_t)row * 512 + bn + coll] = (__bf16)v;
            }
#pragma unroll
            for (int off = 1; off < 16; off <<= 1) {
                ps += __shfl_xor(ps, off);
                pd += __shfl_xor(pd, off);
            }
            if (m16 == 0) { atomicAdd(&sA[rowl], ps); atomicAdd(&sD[rowl], pd); }
        }
    }
    __syncthreads();
    if (tid < 64) {
        int row = bi + tid;
        if (row < NN) { asrc[row * 4 + ct] = sA[tid]; adst[row * 4 + ct] = sD[tid]; }
    }
}

// ---------------------------------------------------------------------------
// Generic fp32-accum tiled GEMM (small GEMMs), templated output type
// ---------------------------------------------------------------------------
template<bool RELU, bool BIAS, typename OUT>
__global__ void gemm_kernel(const float* __restrict__ A, int lda,
                            const float* __restrict__ B, int ldb,
                            OUT* __restrict__ C, int ldc,
                            const float* __restrict__ bias,
                            int M, int N, int K) {
    __shared__ float As[16][65];
    __shared__ float Bs[16][64];
    int bi = blockIdx.y * 64, bj = blockIdx.x * 64;
    int tid = threadIdx.x;
    int tx = tid & 15, ty = tid >> 4;
    float acc[4][4] = {};
    for (int k0 = 0; k0 < K; k0 += 16) {
        {
            int kk = tid & 15, mm = tid >> 4;
#pragma unroll
            for (int it = 0; it < 4; it++) {
                int row = mm + 16 * it;
                int gr = bi + row;
                As[kk][row] = (gr < M) ? A[(size_t)gr * lda + k0 + kk] : 0.f;
            }
        }
        {
            int nn = tid & 63, kk = tid >> 6;
#pragma unroll
            for (int it = 0; it < 4; it++)
                Bs[kk + 4 * it][nn] = B[(size_t)(k0 + kk + 4 * it) * ldb + bj + nn];
        }
        __syncthreads();
#pragma unroll
        for (int kk = 0; kk < 16; kk++) {
            float av[4], bv[4];
#pragma unroll
            for (int a = 0; a < 4; a++) av[a] = As[kk][ty * 4 + a];
#pragma unroll
            for (int b = 0; b < 4; b++) bv[b] = Bs[kk][tx * 4 + b];
#pragma unroll
            for (int a = 0; a < 4; a++)
#pragma unroll
                for (int b = 0; b < 4; b++)
                    acc[a][b] += av[a] * bv[b];
        }
        __syncthreads();
    }
#pragma unroll
    for (int a = 0; a < 4; a++) {
        int gr = bi + ty * 4 + a;
        if (gr >= M) continue;
#pragma unroll
        for (int b = 0; b < 4; b++) {
            int gc = bj + tx * 4 + b;
            float v = acc[a][b];
            if (BIAS) v += bias[gc];
            if (RELU) v = fmaxf(v, 0.f);
            C[(size_t)gr * ldc + gc] = (OUT)v;
        }
    }
}

// ---------------------------------------------------------------------------
// Fused segment-softmax + aggregation + head-mean + bias + LN + ReLU.
// Phase 1 caches src ids + exp values in LDS (CAP edges); phase 2's critical
// path is then LDS-read -> h gather only. Fallback recompute for deg > CAP.
// ---------------------------------------------------------------------------
template<int H>
__global__ void gat_agg_kernel(const __bf16* __restrict__ hb,
                               const float* __restrict__ asrc,
                               const float* __restrict__ adst,
                               const int* __restrict__ rowstart,
                               const int* __restrict__ csr_src,
                               const float* __restrict__ bias,
                               const float* __restrict__ gamma,
                               const float* __restrict__ beta,
                               float* __restrict__ out) {
    constexpr int CH = H * 128;
    constexpr int CAP = 128;
    int n = blockIdx.x;
    int t = threadIdx.x;
    int w = t >> 6, l = t & 63;
    __shared__ float invden[H];
    __shared__ float denw[4][H];
    __shared__ int   srcs[CAP];
    __shared__ float evs[CAP * H];
    __shared__ float sm[4 * CH];
    __shared__ float red[8];

    int s0 = rowstart[n];
    int deg = rowstart[n + 1] - s0;
    float adst_n = (l < H) ? adst[n * H + l] : 0.f;

    // phase 1: denominators + cache src/ev
    float dloc = 0.f;
    for (int idx = w; idx < deg; idx += 4) {
        int src = csr_src[s0 + idx];
        if (idx < CAP && l == 0) srcs[idx] = src;
        if (l < H) {
            float al = asrc[src * H + l] + adst_n;
            al = al >= 0.f ? al : 0.2f * al;
            float ev = __expf(al);
            dloc += ev;
            if (idx < CAP) evs[idx * H + l] = ev;
        }
    }
    if (l < H) denw[w][l] = dloc;
    __syncthreads();
    if (t < H) invden[t] = 1.f / (denw[0][t] + denw[1][t] + denw[2][t] + denw[3][t]);
    __syncthreads();

    // phase 2: weighted feature accumulation from cached LDS, 2-edge pipelined
    constexpr int NA = (H == 6) ? 12 : 8;
    float acc[NA] = {};
    const int h0 = l >> 4;
    const int h1i = 4 + (l >> 5);
    int degc = deg < CAP ? deg : CAP;
    int idx = w;
    for (; idx + 4 < degc; idx += 8) {
        int src0 = srcs[idx], src1 = srcs[idx + 4];
        float w00 = evs[idx * H + h0];
        float w10 = evs[(idx + 4) * H + h0];
        const __bf16* hp0 = hb + (size_t)src0 * CH;
        const __bf16* hp1 = hb + (size_t)src1 * CH;
        bf16x8 g00 = *(const bf16x8*)(hp0 + l * 8);
        bf16x8 g10 = *(const bf16x8*)(hp1 + l * 8);
#pragma unroll
        for (int jj = 0; jj < 8; jj++)
            acc[jj] += (float)g00[jj] * w00 + (float)g10[jj] * w10;
        if (H == 6) {
            float w01 = evs[idx * H + h1i];
            float w11 = evs[(idx + 4) * H + h1i];
            bf16x4 g01 = *(const bf16x4*)(hp0 + 512 + l * 4);
            bf16x4 g11 = *(const bf16x4*)(hp1 + 512 + l * 4);
#pragma unroll
            for (int jj = 0; jj < 4; jj++)
                acc[8 + jj] += (float)g01[jj] * w01 + (float)g11[jj] * w11;
        }
    }
    if (idx < degc) {
        int src = srcs[idx];
        float w0 = evs[idx * H + h0];
        const __bf16* hp = hb + (size_t)src * CH;
        bf16x8 hv = *(const bf16x8*)(hp + l * 8);
#pragma unroll
        for (int jj = 0; jj < 8; jj++) acc[jj] += (float)hv[jj] * w0;
        if (H == 6) {
            float w1 = evs[idx * H + h1i];
            bf16x4 hv1 = *(const bf16x4*)(hp + 512 + l * 4);
#pragma unroll
            for (int jj = 0; jj < 4; jj++) acc[8 + jj] += (float)hv1[jj] * w1;
        }
    }
    // fallback: uncached edges (deg > CAP; effectively never for this graph)
    for (int i2 = CAP + w; i2 < deg; i2 += 4) {
        int src = csr_src[s0 + i2];
        float ev = 0.f;
        if (l < H) {
            float al = asrc[src * H + l] + adst_n;
            al = al >= 0.f ? al : 0.2f * al;
            ev = __expf(al);
        }
        const __bf16* hp = hb + (size_t)src * CH;
        float wgt = __shfl(ev, h0);
        bf16x8 hv = *(const bf16x8*)(hp + l * 8);
#pragma unroll
        for (int jj = 0; jj < 8; jj++) acc[jj] += (float)hv[jj] * wgt;
        if (H == 6) {
            float wg1 = __shfl(ev, h1i);
            bf16x4 hv1 = *(const bf16x4*)(hp + 512 + l * 4);
#pragma unroll
            for (int jj = 0; jj < 4; jj++) acc[8 + jj] += (float)hv1[jj] * wg1;
        }
    }

    *(f32x4*)(sm + w * CH + l * 8)     = *(f32x4*)(acc);
    *(f32x4*)(sm + w * CH + l * 8 + 4) = *(f32x4*)(acc + 4);
    if (H == 6)
        *(f32x4*)(sm + w * CH + 512 + l * 4) = *(f32x4*)(acc + 8);
    __syncthreads();

    float v = 0.f;
    if (t < 128) {
#pragma unroll
        for (int hh = 0; hh < H; hh++) {
            float hsum = 0.f;
#pragma unroll
            for (int ww = 0; ww < 4; ww++) hsum += sm[ww * CH + hh * 128 + t];
            v += hsum * invden[hh];
        }
        v = v * (1.f / H) + bias[t];
    }
    float sv = (t < 128) ? v : 0.f;
    float sq = (t < 128) ? v * v : 0.f;
#pragma unroll
    for (int off = 32; off; off >>= 1) {
        sv += __shfl_down(sv, off);
        sq += __shfl_down(sq, off);
    }
    if ((t & 63) == 0) { red[w * 2] = sv; red[w * 2 + 1] = sq; }
    __syncthreads();
    float tot = red[0] + red[2] + red[4] + red[6];
    float tsq = red[1] + red[3] + red[5] + red[7];
    float mu = tot * (1.f / 128.f);
    float var = tsq * (1.f / 128.f) - mu * mu;
    float r = rsqrtf(var + 1e-5f);
    if (t < 128) {
        float o = (v - mu) * r * gamma[t] + beta[t];
        out[(size_t)n * 128 + t] = fmaxf(o, 0.f);
    }
}

// per-node GCN aggregation from bf16 y; fp32 cat slice + optional swizzled bf16
__global__ void gcn_agg_kernel(const __bf16* __restrict__ y, int C,
                               const float* __restrict__ dinv,
                               const int* __restrict__ rowstart,
                               const int* __restrict__ csr_src,
                               const float* __restrict__ bias,
                               float* __restrict__ out, int ldo, int coloff,
                               __bf16* __restrict__ bout) {
    int n = blockIdx.x;
    int t = threadIdx.x;  // blockDim == C
    float acc = 0.f;
    int s0 = rowstart[n], s1 = rowstart[n + 1];
    for (int s = s0; s < s1; s++) {
        int src = csr_src[s];
        acc += (float)y[(size_t)src * C + t] * dinv[src];
    }
    float v = fmaxf(acc * dinv[n] + bias[t], 0.f);
    out[(size_t)n * ldo + coloff + t] = v;
    if (bout) {
        // swizzled layout for mfma_gemm2: idx = ((rt*16 + p)*64 + r)*8 + off
        int rt = n >> 6, r = n & 63, p = t >> 3, off = t & 7;
        bout[((size_t)(rt * 16 + p) * 64 + r) * 8 + off] = (__bf16)v;
    }
}

// ---------------------------------------------------------------------------
// Fused: fused=relu(cat@W_fuse+b_fuse); v=fused+relu(skippre+b_skip);
// LN(v) -> 64->32->16->5 MLP. 4 nodes/block (one per wave), W_fuse in LDS.
// ---------------------------------------------------------------------------
__global__ __launch_bounds__(256)
void fuse_final_kernel(const float* __restrict__ cat,
                       const float* __restrict__ skippre,
                       const float* __restrict__ Wf, const float* __restrict__ bfz,
                       const float* __restrict__ b_skip,
                       const float* __restrict__ g3, const float* __restrict__ be3,
                       const float* __restrict__ Wc1, const float* __restrict__ bc1,
                       const float* __restrict__ Wc2, const float* __restrict__ bc2,
                       const float* __restrict__ Wc3, const float* __restrict__ bc3,
                       float* __restrict__ out) {
    __shared__ float WfS[192 * 64];     // 48 KB
    __shared__ float catS[4][196];
    __shared__ float fS[4][64], h1S[4][32], h2S[4][16];
    int tid = threadIdx.x;
    int w = tid >> 6, l = tid & 63;
#pragma unroll
    for (int i = 0; i < 12; i++) {
        int idx = (i * 256 + tid) * 4;
        *(f32x4*)(WfS + idx) = *(const f32x4*)(Wf + idx);
    }
    int n = blockIdx.x * 4 + w;
    bool act = n < NN;
    float sk = 0.f;
    if (act) {
        catS[w][l]       = cat[(size_t)n * 192 + l];
        catS[w][64 + l]  = cat[(size_t)n * 192 + 64 + l];
        catS[w][128 + l] = cat[(size_t)n * 192 + 128 + l];
        sk = fmaxf(skippre[(size_t)n * 64 + l] + b_skip[l], 0.f);
    }
    __syncthreads();

    float fu = bfz[l];
#pragma unroll 4
    for (int k = 0; k < 192; k++)
        fu += catS[w][k] * WfS[k * 64 + l];
    float v = fmaxf(fu, 0.f) + sk;

    float sv = v, sq = v * v;
#pragma unroll
    for (int off = 32; off; off >>= 1) {
        sv += __shfl_xor(sv, off);
        sq += __shfl_xor(sq, off);
    }
    float mu = sv * (1.f / 64.f);
    float var = sq * (1.f / 64.f) - mu * mu;
    float r = rsqrtf(var + 1e-5f);
    fS[w][l] = (v - mu) * r * g3[l] + be3[l];
    __syncthreads();
    if (l < 32) {
        float a = bc1[l];
        for (int i = 0; i < 64; i++) a += fS[w][i] * Wc1[i * 32 + l];
        h1S[w][l] = fmaxf(a, 0.f);
    }
    __syncthreads();
    if (l < 16) {
        float a = bc2[l];
        for (int i = 0; i < 32; i++) a += h1S[w][i] * Wc2[i * 16 + l];
        h2S[w][l] = fmaxf(a, 0.f);
    }
    __syncthreads();
    if (l < 5 && act) {
        float a = bc3[l];
        for (int i = 0; i < 16; i++) a += h2S[w][i] * Wc3[i * 5 + l];
        out[(size_t)n * 5 + l] = a;
    }
}

// ---------------------------------------------------------------------------
extern "C" void kernel_launch(void* const* d_in, const int* in_sizes, int n_in,
                              void* d_out, int out_size, void* d_ws, size_t ws_size,
                              hipStream_t stream) {
    const float* x      = (const float*)d_in[0];
    const int*   ei     = (const int*)d_in[1];
    const float* W_gat1 = (const float*)d_in[2];
    const float* a_src1 = (const float*)d_in[3];
    const float* a_dst1 = (const float*)d_in[4];
    const float* b_gat1 = (const float*)d_in[5];
    const float* W_gcn1 = (const float*)d_in[6];
    const float* b_gcn1 = (const float*)d_in[7];
    const float* W_gat2 = (const float*)d_in[8];
    const float* a_src2 = (const float*)d_in[9];
    const float* a_dst2 = (const float*)d_in[10];
    const float* b_gat2 = (const float*)d_in[11];
    const float* W_gcn2 = (const float*)d_in[12];
    const float* b_gcn2 = (const float*)d_in[13];
    const float* W_skip = (const float*)d_in[14];
    const float* b_skip = (const float*)d_in[15];
    const float* W_fuse = (const float*)d_in[16];
    const float* b_fuse = (const float*)d_in[17];
    const float* W_c1   = (const float*)d_in[18];
    const float* b_c1   = (const float*)d_in[19];
    const float* W_c2   = (const float*)d_in[20];
    const float* b_c2   = (const float*)d_in[21];
    const float* W_c3   = (const float*)d_in[22];
    const float* b_c3   = (const float*)d_in[23];
    const float* g1     = (const float*)d_in[24];
    const float* be1    = (const float*)d_in[25];
    const float* g2     = (const float*)d_in[26];
    const float* be2    = (const float*)d_in[27];
    const float* g3     = (const float*)d_in[28];
    const float* be3    = (const float*)d_in[29];
    float* out = (float*)d_out;

    // workspace arena
    char* p = (char*)d_ws;
    auto alloc = [&](size_t bytes) {
        char* r = p; p += (bytes + 255) & ~(size_t)255; return r;
    };
    __bf16* xb      = (__bf16*)alloc((size_t)MPAD * KPAD * 2);   // 41.4 MB (swizzled)
    __bf16* wt      = (__bf16*)alloc((size_t)NPAD * KPAD * 2);   // 3.7 MB  (swizzled)
    __bf16* w2t     = (__bf16*)alloc((size_t)512 * 128 * 2);     // swizzled
    __bf16* h1b     = (__bf16*)alloc((size_t)NN * 768 * 2);      // 15.4 MB
    __bf16* h2b     = (__bf16*)alloc((size_t)NN * 512 * 2);      // 10.2 MB
    __bf16* ybufb   = (__bf16*)alloc((size_t)NN * 128 * 2);      // y1 reused y2
    __bf16* x1gcnb  = (__bf16*)alloc((size_t)MPAD * 128 * 2);    // swizzled, MFMA2 A
    float* asrc     = (float*)alloc((size_t)NN * 6 * 4);
    float* adst     = (float*)alloc((size_t)NN * 6 * 4);
    int*   deg      = (int*)  alloc((size_t)2 * NN * 4);         // deg | cursor
    int*   cursor   = deg + NN;
    float* dinv     = (float*)alloc((size_t)NN * 4);
    int*   rowst    = (int*)  alloc((size_t)(NN + 1) * 4);
    int*   csrc     = (int*)  alloc((size_t)ET * 4);
    float* x1gat    = (float*)alloc((size_t)NN * 128 * 4);
    float* cat      = (float*)alloc((size_t)NN * 192 * 4);
    float* x2gat    = (float*)alloc((size_t)NN * 128 * 4);
    float* skippre  = (float*)alloc((size_t)NN * 64 * 4);

    hipMemsetAsync(deg, 0, (size_t)2 * NN * 4, stream);
    hipMemsetAsync(x1gcnb, 0, (size_t)MPAD * 128 * 2, stream);  // pad rows interleaved

    const int EB = (ET + 255) / 256;
    const int MB = (NN + 63) / 64;

    // merged bf16 conversions (swizzled layouts)
    const int WBLK = (NW1 + 512 * 128 / 8 + 255) / 256;
    conv_kernel<<<NBX + WBLK, 256, 0, stream>>>(x, xb, W_gat1, W_skip, W_gat2, wt, w2t);

    // CSR by dst
    count_kernel  <<<EB, 256, 0, stream>>>(ei, deg);
    scan_kernel   <<<1, 256, 0, stream>>>(deg, rowst, dinv);
    scatter_kernel<<<EB, 256, 0, stream>>>(ei, rowst, cursor, csrc);

    // h1 (bf16) + skippre + fused alpha1, XCD-swizzled 128x128 BK=64, 4 waves
    mfma_gemm1_kernel<<<560, 256, 0, stream>>>(xb, wt, a_src1, a_dst1,
                                               h1b, skippre, asrc, adst);

    // ---- GAT layer 1 (H=6) ----
    gat_agg_kernel<6><<<NN, 256, 0, stream>>>(h1b, asrc, adst, rowst, csrc,
                                              b_gat1, g1, be1, x1gat);
    // ---- GCN layer 1 (fp32 GEMM -> bf16 y) ----
    gemm_kernel<false, false, __bf16><<<dim3(2, MB), 256, 0, stream>>>(
        x1gat, 128, W_gcn1, 128, ybufb, 128, nullptr, NN, 128, 128);
    gcn_agg_kernel<<<NN, 128, 0, stream>>>(ybufb, 128, dinv, rowst, csrc,
                                           b_gcn1, cat, 192, 0, x1gcnb);
    // ---- GAT layer 2 (H=4): h2 + fused alpha2 (bf16 MFMA, 4 waves) ----
    mfma_gemm2_kernel<<<dim3(4, MPAD / 64), 256, 0, stream>>>(
        x1gcnb, w2t, a_src2, a_dst2, h2b, asrc, adst);
    gat_agg_kernel<4><<<NN, 256, 0, stream>>>(h2b, asrc, adst, rowst, csrc,
                                              b_gat2, g2, be2, x2gat);
    // ---- GCN layer 2 (fp32 GEMM -> bf16 y) -> cat[:, 128:192] ----
    gemm_kernel<false, false, __bf16><<<dim3(1, MB), 256, 0, stream>>>(
        x2gat, 128, W_gcn2, 64, ybufb, 64, nullptr, NN, 64, 128);
    gcn_agg_kernel<<<NN, 64, 0, stream>>>(ybufb, 64, dinv, rowst, csrc,
                                          b_gcn2, cat, 192, 128, nullptr);
    // ---- fuse + final (merged) ----
    fuse_final_kernel<<<(NN + 3) / 4, 256, 0, stream>>>(
        cat, skippre, W_fuse, b_fuse, b_skip, g3, be3,
        W_c1, b_c1, W_c2, b_c2, W_c3, b_c3, out);
}

// Round 11
// 522.238 us; speedup vs baseline: 1.0002x; 1.0002x over previous
//
#include <hip/hip_runtime.h>
#include <cstdint>
#include <cstddef>

#define NN 10000
#define NE 160000
#define ET (NE + NN)          // edges + self loops
#define FIN 2000
#define MPAD 10112            // 158 * 64
#define KPAD 2048
#define NPAD 896              // 7 * 128 (768 gat1 cols + 64 skip + 64 pad)

typedef __bf16 bf16x8 __attribute__((ext_vector_type(8)));
typedef __bf16 bf16x4 __attribute__((ext_vector_type(4)));
typedef float  f32x4  __attribute__((ext_vector_type(4)));

#define GLL(src, dst) __builtin_amdgcn_global_load_lds( \
    (const __attribute__((address_space(1))) void*)(src), \
    (__attribute__((address_space(3))) void*)(dst), 16, 0, 0)

// ---------------------------------------------------------------------------
// CSR build
// ---------------------------------------------------------------------------
__device__ __forceinline__ void edge_sd(const int* ei, int e, int& s, int& d) {
    if (e < NE) { s = ei[e]; d = ei[NE + e]; }
    else        { s = e - NE; d = e - NE; }
}

// exclusive scan over deg -> rowstart[0..NN]; also dinv = deg^-1/2
__global__ void scan_kernel(const int* deg, int* rowstart, float* dinv) {
    __shared__ int partial[256];
    const int T = 256;
    int chunk = (NN + T - 1) / T;
    int t = threadIdx.x;
    int begin = t * chunk;
    int end = begin + chunk; if (end > NN) end = NN;
    int s = 0;
    for (int i = begin; i < end && i >= begin; i++) s += deg[i];
    partial[t] = s;
    __syncthreads();
    if (t == 0) {
        int run = 0;
        for (int i = 0; i < T; i++) { int v = partial[i]; partial[i] = run; run += v; }
    }
    __syncthreads();
    int run = partial[t];
    for (int i = begin; i < end && i >= begin; i++) {
        rowstart[i] = run; run += deg[i];
        int dg = deg[i];
        dinv[i] = dg > 0 ? rsqrtf((float)dg) : 0.f;
    }
    if (end == NN && begin <= NN) rowstart[NN] = run;
}

__global__ void scatter_kernel(const int* ei, const int* rowstart, int* cursor,
                               int* csr_src) {
    int e = blockIdx.x * blockDim.x + threadIdx.x;
    if (e >= ET) return;
    int s, d; edge_sd(ei, e, s, d);
    int pos = atomicAdd(&cursor[d], 1);
    csr_src[rowstart[d] + pos] = s;
}

// ---------------------------------------------------------------------------
// Merged conversion + degree count.
// Blocks [0, NBX): xb slab transpose via LDS (coalesced read AND write).
// Blocks [NBX, NBX+WBLK): wt / w2t conversion.
// Blocks [NBX+WBLK, ...): edge degree count (atomicAdd into deg).
// xb chunk c = ((rt*32 + ks)*8 + p)*64 + r holds x[rt*64+r][ks*64+p*8 ..+8)
// wt chunk: ((ct*32 + ks)*8 + p)*128 + r ; w2t chunk: (ct*16 + p)*128 + r
// ---------------------------------------------------------------------------
#define NBX (158 * 32)
#define NW1 (NPAD * KPAD / 8)                 // 229376
#define NWT (NW1 + 512 * 128 / 8)             // 237568
#define WBLK 928                               // NWT / 256
#define EB 665                                 // ceil(ET/256)
__global__ void conv_kernel(const float* __restrict__ x, __bf16* __restrict__ xb,
                            const float* __restrict__ Wg, const float* __restrict__ Ws,
                            const float* __restrict__ W2,
                            __bf16* __restrict__ wt, __bf16* __restrict__ w2t,
                            const int* __restrict__ ei, int* __restrict__ deg) {
    __shared__ __bf16 slab[4096];   // 8 planes x 64 rows x 8 = output chunk layout
    int bid = blockIdx.x;
    int tid = threadIdx.x;
    if (bid < NBX) {
        int rt = bid >> 5, ks = bid & 31;
        int r = tid >> 2;                 // 0..63
        int row = rt * 64 + r;
        int c0 = (tid & 3) * 16;          // 0,16,32,48
        int kbase = ks * 64;
#pragma unroll
        for (int j = 0; j < 4; j++) {
            int kl = c0 + j * 4;          // local k, mult of 4
            int k = kbase + kl;
            bf16x4 o;
            if (row < NN && k + 3 < FIN) {
                float4 v = *(const float4*)(x + (size_t)row * FIN + k);
                o[0] = (__bf16)v.x; o[1] = (__bf16)v.y;
                o[2] = (__bf16)v.z; o[3] = (__bf16)v.w;
            } else {
                o[0] = o[1] = o[2] = o[3] = (__bf16)0.f;
            }
            int p = kl >> 3, off = kl & 7;
            *(bf16x4*)(slab + (p * 64 + r) * 8 + off) = o;
        }
        __syncthreads();
        size_t base = (size_t)(rt * 32 + ks) * 512;   // chunk index
#pragma unroll
        for (int i = 0; i < 2; i++) {
            int c = i * 256 + tid;
            *(bf16x8*)(xb + (base + c) * 8) = *(const bf16x8*)(slab + c * 8);
        }
    } else if (bid < NBX + WBLK) {
        int g = (bid - NBX) * 256 + tid;
        if (g < NW1) {
            int r = g & 127, p = (g >> 7) & 7, ks = (g >> 10) & 31, ct = g >> 15;
            int n = ct * 128 + r;
            int k0 = ks * 64 + p * 8;
            bf16x8 o;
#pragma unroll
            for (int j = 0; j < 8; j++) {
                int k = k0 + j;
                float v = 0.f;
                if (k < FIN) {
                    if (n < 768)      v = Wg[(size_t)k * 768 + n];
                    else if (n < 832) v = Ws[(size_t)k * 64 + (n - 768)];
                }
                o[j] = (__bf16)v;
            }
            *(bf16x8*)(wt + (size_t)g * 8) = o;
        } else if (g < NWT) {
            int g2 = g - NW1;
            int c = g2 & 2047;
            int ct = g2 >> 11;
            int p = c >> 7, r = c & 127;
            int n = ct * 128 + r;
            int k0 = p * 8;
            bf16x8 o;
#pragma unroll
            for (int j = 0; j < 8; j++)
                o[j] = (__bf16)W2[(size_t)(k0 + j) * 512 + n];
            *(bf16x8*)(w2t + (size_t)g2 * 8) = o;
        }
    } else {
        int e = (bid - NBX - WBLK) * 256 + tid;
        if (e < ET) {
            int s, d; edge_sd(ei, e, s, d);
            atomicAdd(&deg[d], 1);
        }
    }
}

// ---------------------------------------------------------------------------
// MFMA GEMM 1: xb @ wt^T -> h1b bf16[NN,768], skippre f32[NN,64], + fused
// alpha1. 64M x 128N block, 4 waves (32x64 each, 2x2), BK=64. 256 threads.
// (round-8/9 verified plateau shape: VGPR ~60, 4480 waves)
// ---------------------------------------------------------------------------
__global__ __launch_bounds__(256)
void mfma_gemm1_kernel(const __bf16* __restrict__ xb, const __bf16* __restrict__ wt,
                       const float* __restrict__ a_src1, const float* __restrict__ a_dst1,
                       __bf16* __restrict__ h1b, float* __restrict__ skippre,
                       float* __restrict__ asrc, float* __restrict__ adst) {
    __shared__ __bf16 As[4096];    // 8 planes x 64 rows x 8  (8 KB)
    __shared__ __bf16 Bs[8192];    // 8 planes x 128 rows x 8 (16 KB)
    __shared__ float sA[64], sD[64];
    __shared__ float asd[256];
    int b = blockIdx.x;
    int xcd = b & 7, j = b >> 3;
    int jq = j / 7;
    int rt = xcd + 8 * jq;
    int ct = j - 7 * jq;
    if (rt >= MPAD / 64) return;
    const int bi = rt * 64;
    const int bn = ct * 128;

    const int tid = threadIdx.x;
    const int lane = tid & 63;
    const int w = tid >> 6;
    const int wm = w >> 1, wn = w & 1;
    const int q = lane >> 4, m16 = lane & 15;

    if (tid < 64) { sA[tid] = 0.f; sD[tid] = 0.f; }
    if (ct < 6) {
        if (tid < 128) asd[tid] = a_src1[ct * 128 + tid];
        else           asd[tid] = a_dst1[ct * 128 + (tid - 128)];
    }

    f32x4 acc[2][4] = {};

    for (int ks = 0; ks < KPAD / 64; ks++) {
        const size_t slabA = (size_t)(rt * 32 + ks) * 512;
        const size_t slabB = (size_t)(ct * 32 + ks) * 1024;
#pragma unroll
        for (int i = 0; i < 2; i++) {
            int seg = i * 4 + w;
            GLL(xb + (slabA + seg * 64 + lane) * 8, As + seg * 512);
        }
#pragma unroll
        for (int i = 0; i < 4; i++) {
            int seg = i * 4 + w;
            GLL(wt + (slabB + seg * 64 + lane) * 8, Bs + seg * 512);
        }
        __syncthreads();

#pragma unroll
        for (int kk = 0; kk < 2; kk++) {
            const int pb = kk * 4 + q;
            bf16x8 af[2], bfr[4];
#pragma unroll
            for (int mt = 0; mt < 2; mt++)
                af[mt] = *(const bf16x8*)(As + (pb * 64 + wm * 32 + mt * 16 + m16) * 8);
#pragma unroll
            for (int nt = 0; nt < 4; nt++)
                bfr[nt] = *(const bf16x8*)(Bs + (pb * 128 + wn * 64 + nt * 16 + m16) * 8);
#pragma unroll
            for (int mt = 0; mt < 2; mt++)
#pragma unroll
                for (int nt = 0; nt < 4; nt++)
                    acc[mt][nt] = __builtin_amdgcn_mfma_f32_16x16x32_bf16(af[mt], bfr[nt], acc[mt][nt], 0, 0, 0);
        }
        __syncthreads();
    }

#pragma unroll
    for (int mt = 0; mt < 2; mt++) {
#pragma unroll
        for (int r = 0; r < 4; r++) {
            int rowl = wm * 32 + mt * 16 + q * 4 + r;
            int row = bi + rowl;
            float ps = 0.f, pd = 0.f;
#pragma unroll
            for (int nt = 0; nt < 4; nt++) {
                int coll = wn * 64 + nt * 16 + m16;
                int col = bn + coll;
                float v = acc[mt][nt][r];
                if (ct < 6) { ps += v * asd[coll]; pd += v * asd[128 + coll]; }
                if (row < NN) {
                    if (col < 768)      h1b[(size_t)row * 768 + col] = (__bf16)v;
                    else if (col < 832) skippre[(size_t)row * 64 + (col - 768)] = v;
                }
            }
            if (ct < 6) {
#pragma unroll
                for (int off = 1; off < 16; off <<= 1) {
                    ps += __shfl_xor(ps, off);
                    pd += __shfl_xor(pd, off);
                }
                if (m16 == 0) { atomicAdd(&sA[rowl], ps); atomicAdd(&sD[rowl], pd); }
            }
        }
    }
    if (ct < 6) {
        __syncthreads();
        if (tid < 64) {
            int row = bi + tid;
            if (row < NN) { asrc[row * 6 + ct] = sA[tid]; adst[row * 6 + ct] = sD[tid]; }
        }
    }
}

// ---------------------------------------------------------------------------
// MFMA GEMM 2: x1gcnb(swizzled)[MPAD,128] @ w2t(swizzled)[512,128]^T -> h2b
// bf16[NN,512], + fused alpha2. 64x128 block, 4 waves (32x64), BK=64, 256 thr.
// ---------------------------------------------------------------------------
__global__ __launch_bounds__(256)
void mfma_gemm2_kernel(const __bf16* __restrict__ A, const __bf16* __restrict__ B,
                       const float* __restrict__ a_src2, const float* __restrict__ a_dst2,
                       __bf16* __restrict__ h2b,
                       float* __restrict__ asrc, float* __restrict__ adst) {
    __shared__ __bf16 As[4096];
    __shared__ __bf16 Bs[8192];
    __shared__ float sA[64], sD[64];
    __shared__ float asd[256];
    const int rt = blockIdx.y, ct = blockIdx.x;
    const int bi = rt * 64, bn = ct * 128;
    const int tid = threadIdx.x, lane = tid & 63, w = tid >> 6;
    const int wm = w >> 1, wn = w & 1;
    const int q = lane >> 4, m16 = lane & 15;

    if (tid < 64) { sA[tid] = 0.f; sD[tid] = 0.f; }
    if (tid < 128) asd[tid] = a_src2[ct * 128 + tid];
    else           asd[tid] = a_dst2[ct * 128 + (tid - 128)];

    f32x4 acc[2][4] = {};

    for (int ks = 0; ks < 2; ks++) {
        const size_t slabA = (size_t)rt * 1024 + ks * 512;
        const size_t slabB = (size_t)ct * 2048 + ks * 1024;
#pragma unroll
        for (int i = 0; i < 2; i++) {
            int seg = i * 4 + w;
            GLL(A + (slabA + seg * 64 + lane) * 8, As + seg * 512);
        }
#pragma unroll
        for (int i = 0; i < 4; i++) {
            int seg = i * 4 + w;
            GLL(B + (slabB + seg * 64 + lane) * 8, Bs + seg * 512);
        }
        __syncthreads();

#pragma unroll
        for (int kk = 0; kk < 2; kk++) {
            const int pb = kk * 4 + q;
            bf16x8 af[2], bfr[4];
#pragma unroll
            for (int mt = 0; mt < 2; mt++)
                af[mt] = *(const bf16x8*)(As + (pb * 64 + wm * 32 + mt * 16 + m16) * 8);
#pragma unroll
            for (int nt = 0; nt < 4; nt++)
                bfr[nt] = *(const bf16x8*)(Bs + (pb * 128 + wn * 64 + nt * 16 + m16) * 8);
#pragma unroll
            for (int mt = 0; mt < 2; mt++)
#pragma unroll
                for (int nt = 0; nt < 4; nt++)
                    acc[mt][nt] = __builtin_amdgcn_mfma_f32_16x16x32_bf16(af[mt], bfr[nt], acc[mt][nt], 0, 0, 0);
        }
        __syncthreads();
    }

#pragma unroll
    for (int mt = 0; mt < 2; mt++) {
#pragma unroll
        for (int r = 0; r < 4; r++) {
            int rowl = wm * 32 + mt * 16 + q * 4 + r;
            int row = bi + rowl;
            float ps = 0.f, pd = 0.f;
#pragma unroll
            for (int nt = 0; nt < 4; nt++) {
                int coll = wn * 64 + nt * 16 + m16;
                float v = acc[mt][nt][r];
                ps += v * asd[coll]; pd += v * asd[128 + coll];
                if (row < NN) h2b[(size_t)row * 512 + bn + coll] = (__bf16)v;
            }
#pragma unroll
            for (int off = 1; off < 16; off <<= 1) {
                ps += __shfl_xor(ps, off);
                pd += __shfl_xor(pd, off);
            }
            if (m16 == 0) { atomicAdd(&sA[rowl], ps); atomicAdd(&sD[rowl], pd); }
        }
    }
    __syncthreads();
    if (tid < 64) {
        int row = bi + tid;
        if (row < NN) { asrc[row * 4 + ct] = sA[tid]; adst[row * 4 + ct] = sD[tid]; }
    }
}

// ---------------------------------------------------------------------------
// Generic fp32-accum tiled GEMM (small GEMMs), templated output type
// ---------------------------------------------------------------------------
template<bool RELU, bool BIAS, typename OUT>
__global__ void gemm_kernel(const float* __restrict__ A, int lda,
                            const float* __restrict__ B, int ldb,
                            OUT* __restrict__ C, int ldc,
                            const float* __restrict__ bias,
                            int M, int N, int K) {
    __shared__ float As[16][65];
    __shared__ float Bs[16][64];
    int bi = blockIdx.y * 64, bj = blockIdx.x * 64;
    int tid = threadIdx.x;
    int tx = tid & 15, ty = tid >> 4;
    float acc[4][4] = {};
    for (int k0 = 0; k0 < K; k0 += 16) {
        {
            int kk = tid & 15, mm = tid >> 4;
#pragma unroll
            for (int it = 0; it < 4; it++) {
                int row = mm + 16 * it;
                int gr = bi + row;
                As[kk][row] = (gr < M) ? A[(size_t)gr * lda + k0 + kk] : 0.f;
            }
        }
        {
            int nn = tid & 63, kk = tid >> 6;
#pragma unroll
            for (int it = 0; it < 4; it++)
                Bs[kk + 4 * it][nn] = B[(size_t)(k0 + kk + 4 * it) * ldb + bj + nn];
        }
        __syncthreads();
#pragma unroll
        for (int kk = 0; kk < 16; kk++) {
            float av[4], bv[4];
#pragma unroll
            for (int a = 0; a < 4; a++) av[a] = As[kk][ty * 4 + a];
#pragma unroll
            for (int b = 0; b < 4; b++) bv[b] = Bs[kk][tx * 4 + b];
#pragma unroll
            for (int a = 0; a < 4; a++)
#pragma unroll
                for (int b = 0; b < 4; b++)
                    acc[a][b] += av[a] * bv[b];
        }
        __syncthreads();
    }
#pragma unroll
    for (int a = 0; a < 4; a++) {
        int gr = bi + ty * 4 + a;
        if (gr >= M) continue;
#pragma unroll
        for (int b = 0; b < 4; b++) {
            int gc = bj + tx * 4 + b;
            float v = acc[a][b];
            if (BIAS) v += bias[gc];
            if (RELU) v = fmaxf(v, 0.f);
            C[(size_t)gr * ldc + gc] = (OUT)v;
        }
    }
}

// ---------------------------------------------------------------------------
// Fused segment-softmax + aggregation + head-mean + bias + LN + ReLU.
// Phase 1 caches src ids + exp values in LDS (CAP edges); phase 2's critical
// path is then LDS-read -> h gather only. Fallback recompute for deg > CAP.
// ---------------------------------------------------------------------------
template<int H>
__global__ void gat_agg_kernel(const __bf16* __restrict__ hb,
                               const float* __restrict__ asrc,
                               const float* __restrict__ adst,
                               const int* __restrict__ rowstart,
                               const int* __restrict__ csr_src,
                               const float* __restrict__ bias,
                               const float* __restrict__ gamma,
                               const float* __restrict__ beta,
                               float* __restrict__ out) {
    constexpr int CH = H * 128;
    constexpr int CAP = 128;
    int n = blockIdx.x;
    int t = threadIdx.x;
    int w = t >> 6, l = t & 63;
    __shared__ float invden[H];
    __shared__ float denw[4][H];
    __shared__ int   srcs[CAP];
    __shared__ float evs[CAP * H];
    __shared__ float sm[4 * CH];
    __shared__ float red[8];

    int s0 = rowstart[n];
    int deg = rowstart[n + 1] - s0;
    float adst_n = (l < H) ? adst[n * H + l] : 0.f;

    // phase 1: denominators + cache src/ev
    float dloc = 0.f;
    for (int idx = w; idx < deg; idx += 4) {
        int src = csr_src[s0 + idx];
        if (idx < CAP && l == 0) srcs[idx] = src;
        if (l < H) {
            float al = asrc[src * H + l] + adst_n;
            al = al >= 0.f ? al : 0.2f * al;
            float ev = __expf(al);
            dloc += ev;
            if (idx < CAP) evs[idx * H + l] = ev;
        }
    }
    if (l < H) denw[w][l] = dloc;
    __syncthreads();
    if (t < H) invden[t] = 1.f / (denw[0][t] + denw[1][t] + denw[2][t] + denw[3][t]);
    __syncthreads();

    // phase 2: weighted feature accumulation from cached LDS, 2-edge pipelined
    constexpr int NA = (H == 6) ? 12 : 8;
    float acc[NA] = {};
    const int h0 = l >> 4;
    const int h1i = 4 + (l >> 5);
    int degc = deg < CAP ? deg : CAP;
    int idx = w;
    for (; idx + 4 < degc; idx += 8) {
        int src0 = srcs[idx], src1 = srcs[idx + 4];
        float w00 = evs[idx * H + h0];
        float w10 = evs[(idx + 4) * H + h0];
        const __bf16* hp0 = hb + (size_t)src0 * CH;
        const __bf16* hp1 = hb + (size_t)src1 * CH;
        bf16x8 g00 = *(const bf16x8*)(hp0 + l * 8);
        bf16x8 g10 = *(const bf16x8*)(hp1 + l * 8);
#pragma unroll
        for (int jj = 0; jj < 8; jj++)
            acc[jj] += (float)g00[jj] * w00 + (float)g10[jj] * w10;
        if (H == 6) {
            float w01 = evs[idx * H + h1i];
            float w11 = evs[(idx + 4) * H + h1i];
            bf16x4 g01 = *(const bf16x4*)(hp0 + 512 + l * 4);
            bf16x4 g11 = *(const bf16x4*)(hp1 + 512 + l * 4);
#pragma unroll
            for (int jj = 0; jj < 4; jj++)
                acc[8 + jj] += (float)g01[jj] * w01 + (float)g11[jj] * w11;
        }
    }
    if (idx < degc) {
        int src = srcs[idx];
        float w0 = evs[idx * H + h0];
        const __bf16* hp = hb + (size_t)src * CH;
        bf16x8 hv = *(const bf16x8*)(hp + l * 8);
#pragma unroll
        for (int jj = 0; jj < 8; jj++) acc[jj] += (float)hv[jj] * w0;
        if (H == 6) {
            float w1 = evs[idx * H + h1i];
            bf16x4 hv1 = *(const bf16x4*)(hp + 512 + l * 4);
#pragma unroll
            for (int jj = 0; jj < 4; jj++) acc[8 + jj] += (float)hv1[jj] * w1;
        }
    }
    // fallback: uncached edges (deg > CAP; effectively never for this graph)
    for (int i2 = CAP + w; i2 < deg; i2 += 4) {
        int src = csr_src[s0 + i2];
        float ev = 0.f;
        if (l < H) {
            float al = asrc[src * H + l] + adst_n;
            al = al >= 0.f ? al : 0.2f * al;
            ev = __expf(al);
        }
        const __bf16* hp = hb + (size_t)src * CH;
        float wgt = __shfl(ev, h0);
        bf16x8 hv = *(const bf16x8*)(hp + l * 8);
#pragma unroll
        for (int jj = 0; jj < 8; jj++) acc[jj] += (float)hv[jj] * wgt;
        if (H == 6) {
            float wg1 = __shfl(ev, h1i);
            bf16x4 hv1 = *(const bf16x4*)(hp + 512 + l * 4);
#pragma unroll
            for (int jj = 0; jj < 4; jj++) acc[8 + jj] += (float)hv1[jj] * wg1;
        }
    }

    *(f32x4*)(sm + w * CH + l * 8)     = *(f32x4*)(acc);
    *(f32x4*)(sm + w * CH + l * 8 + 4) = *(f32x4*)(acc + 4);
    if (H == 6)
        *(f32x4*)(sm + w * CH + 512 + l * 4) = *(f32x4*)(acc + 8);
    __syncthreads();

    float v = 0.f;
    if (t < 128) {
#pragma unroll
        for (int hh = 0; hh < H; hh++) {
            float hsum = 0.f;
#pragma unroll
            for (int ww = 0; ww < 4; ww++) hsum += sm[ww * CH + hh * 128 + t];
            v += hsum * invden[hh];
        }
        v = v * (1.f / H) + bias[t];
    }
    float sv = (t < 128) ? v : 0.f;
    float sq = (t < 128) ? v * v : 0.f;
#pragma unroll
    for (int off = 32; off; off >>= 1) {
        sv += __shfl_down(sv, off);
        sq += __shfl_down(sq, off);
    }
    if ((t & 63) == 0) { red[w * 2] = sv; red[w * 2 + 1] = sq; }
    __syncthreads();
    float tot = red[0] + red[2] + red[4] + red[6];
    float tsq = red[1] + red[3] + red[5] + red[7];
    float mu = tot * (1.f / 128.f);
    float var = tsq * (1.f / 128.f) - mu * mu;
    float r = rsqrtf(var + 1e-5f);
    if (t < 128) {
        float o = (v - mu) * r * gamma[t] + beta[t];
        out[(size_t)n * 128 + t] = fmaxf(o, 0.f);
    }
}

// per-node GCN aggregation from bf16 y; fp32 out slice + optional swizzled bf16
__global__ void gcn_agg_kernel(const __bf16* __restrict__ y, int C,
                               const float* __restrict__ dinv,
                               const int* __restrict__ rowstart,
                               const int* __restrict__ csr_src,
                               const float* __restrict__ bias,
                               float* __restrict__ out, int ldo, int coloff,
                               __bf16* __restrict__ bout) {
    int n = blockIdx.x;
    int t = threadIdx.x;  // blockDim == C
    float acc = 0.f;
    int s0 = rowstart[n], s1 = rowstart[n + 1];
    for (int s = s0; s < s1; s++) {
        int src = csr_src[s];
        acc += (float)y[(size_t)src * C + t] * dinv[src];
    }
    float v = fmaxf(acc * dinv[n] + bias[t], 0.f);
    out[(size_t)n * ldo + coloff + t] = v;
    if (bout) {
        // swizzled layout for mfma_gemm2: idx = ((rt*16 + p)*64 + r)*8 + off
        int rt = n >> 6, r = n & 63, p = t >> 3, off = t & 7;
        bout[((size_t)(rt * 16 + p) * 64 + r) * 8 + off] = (__bf16)v;
    }
}

// ---------------------------------------------------------------------------
// Fused: x2_gcn = relu(dinv[n]*sum(y2[src]*dinv[src]) + b_gcn2)  (GCN2 agg)
//        fused  = relu([x1_gcn | x2_gcn] @ W_fuse + b_fuse)
//        v = fused + relu(skippre + b_skip); LN(v) -> 64->32->16->5 MLP.
// 4 nodes/block (one per wave), W_fuse in LDS.
// ---------------------------------------------------------------------------
__global__ __launch_bounds__(256)
void fuse_final_kernel(const float* __restrict__ cat1,
                       const __bf16* __restrict__ y2,
                       const float* __restrict__ dinv,
                       const int* __restrict__ rowstart,
                       const int* __restrict__ csr_src,
                       const float* __restrict__ b_gcn2,
                       const float* __restrict__ skippre,
                       const float* __restrict__ Wf, const float* __restrict__ bfz,
                       const float* __restrict__ b_skip,
                       const float* __restrict__ g3, const float* __restrict__ be3,
                       const float* __restrict__ Wc1, const float* __restrict__ bc1,
                       const float* __restrict__ Wc2, const float* __restrict__ bc2,
                       const float* __restrict__ Wc3, const float* __restrict__ bc3,
                       float* __restrict__ out) {
    __shared__ float WfS[192 * 64];     // 48 KB
    __shared__ float catS[4][196];
    __shared__ float fS[4][64], h1S[4][32], h2S[4][16];
    int tid = threadIdx.x;
    int w = tid >> 6, l = tid & 63;
#pragma unroll
    for (int i = 0; i < 12; i++) {
        int idx = (i * 256 + tid) * 4;
        *(f32x4*)(WfS + idx) = *(const f32x4*)(Wf + idx);
    }
    int n = blockIdx.x * 4 + w;
    bool act = n < NN;
    float sk = 0.f;
    if (act) {
        catS[w][l]      = cat1[(size_t)n * 128 + l];
        catS[w][64 + l] = cat1[(size_t)n * 128 + 64 + l];
        // GCN2 aggregation (same math/order as gcn_agg_kernel)
        float acc2 = 0.f;
        int s0 = rowstart[n], s1 = rowstart[n + 1];
        for (int s = s0; s < s1; s++) {
            int src = csr_src[s];
            acc2 += (float)y2[(size_t)src * 64 + l] * dinv[src];
        }
        catS[w][128 + l] = fmaxf(acc2 * dinv[n] + b_gcn2[l], 0.f);
        sk = fmaxf(skippre[(size_t)n * 64 + l] + b_skip[l], 0.f);
    }
    __syncthreads();

    float fu = bfz[l];
#pragma unroll 4
    for (int k = 0; k < 192; k++)
        fu += catS[w][k] * WfS[k * 64 + l];
    float v = fmaxf(fu, 0.f) + sk;

    float sv = v, sq = v * v;
#pragma unroll
    for (int off = 32; off; off >>= 1) {
        sv += __shfl_xor(sv, off);
        sq += __shfl_xor(sq, off);
    }
    float mu = sv * (1.f / 64.f);
    float var = sq * (1.f / 64.f) - mu * mu;
    float r = rsqrtf(var + 1e-5f);
    fS[w][l] = (v - mu) * r * g3[l] + be3[l];
    __syncthreads();
    if (l < 32) {
        float a = bc1[l];
        for (int i = 0; i < 64; i++) a += fS[w][i] * Wc1[i * 32 + l];
        h1S[w][l] = fmaxf(a, 0.f);
    }
    __syncthreads();
    if (l < 16) {
        float a = bc2[l];
        for (int i = 0; i < 32; i++) a += h1S[w][i] * Wc2[i * 16 + l];
        h2S[w][l] = fmaxf(a, 0.f);
    }
    __syncthreads();
    if (l < 5 && act) {
        float a = bc3[l];
        for (int i = 0; i < 16; i++) a += h2S[w][i] * Wc3[i * 5 + l];
        out[(size_t)n * 5 + l] = a;
    }
}

// ---------------------------------------------------------------------------
extern "C" void kernel_launch(void* const* d_in, const int* in_sizes, int n_in,
                              void* d_out, int out_size, void* d_ws, size_t ws_size,
                              hipStream_t stream) {
    const float* x      = (const float*)d_in[0];
    const int*   ei     = (const int*)d_in[1];
    const float* W_gat1 = (const float*)d_in[2];
    const float* a_src1 = (const float*)d_in[3];
    const float* a_dst1 = (const float*)d_in[4];
    const float* b_gat1 = (const float*)d_in[5];
    const float* W_gcn1 = (const float*)d_in[6];
    const float* b_gcn1 = (const float*)d_in[7];
    const float* W_gat2 = (const float*)d_in[8];
    const float* a_src2 = (const float*)d_in[9];
    const float* a_dst2 = (const float*)d_in[10];
    const float* b_gat2 = (const float*)d_in[11];
    const float* W_gcn2 = (const float*)d_in[12];
    const float* b_gcn2 = (const float*)d_in[13];
    const float* W_skip = (const float*)d_in[14];
    const float* b_skip = (const float*)d_in[15];
    const float* W_fuse = (const float*)d_in[16];
    const float* b_fuse = (const float*)d_in[17];
    const float* W_c1   = (const float*)d_in[18];
    const float* b_c1   = (const float*)d_in[19];
    const float* W_c2   = (const float*)d_in[20];
    const float* b_c2   = (const float*)d_in[21];
    const float* W_c3   = (const float*)d_in[22];
    const float* b_c3   = (const float*)d_in[23];
    const float* g1     = (const float*)d_in[24];
    const float* be1    = (const float*)d_in[25];
    const float* g2     = (const float*)d_in[26];
    const float* be2    = (const float*)d_in[27];
    const float* g3     = (const float*)d_in[28];
    const float* be3    = (const float*)d_in[29];
    float* out = (float*)d_out;

    // workspace arena
    char* p = (char*)d_ws;
    auto alloc = [&](size_t bytes) {
        char* r = p; p += (bytes + 255) & ~(size_t)255; return r;
    };
    __bf16* xb      = (__bf16*)alloc((size_t)MPAD * KPAD * 2);   // 41.4 MB (swizzled)
    __bf16* wt      = (__bf16*)alloc((size_t)NPAD * KPAD * 2);   // 3.7 MB  (swizzled)
    __bf16* w2t     = (__bf16*)alloc((size_t)512 * 128 * 2);     // swizzled
    __bf16* h1b     = (__bf16*)alloc((size_t)NN * 768 * 2);      // 15.4 MB
    __bf16* h2b     = (__bf16*)alloc((size_t)NN * 512 * 2);      // 10.2 MB
    __bf16* ybufb   = (__bf16*)alloc((size_t)NN * 128 * 2);      // y1 reused y2
    __bf16* x1gcnb  = (__bf16*)alloc((size_t)MPAD * 128 * 2);    // swizzled, MFMA2 A
    float* asrc     = (float*)alloc((size_t)NN * 6 * 4);
    float* adst     = (float*)alloc((size_t)NN * 6 * 4);
    int*   deg      = (int*)  alloc((size_t)2 * NN * 4);         // deg | cursor
    int*   cursor   = deg + NN;
    float* dinv     = (float*)alloc((size_t)NN * 4);
    int*   rowst    = (int*)  alloc((size_t)(NN + 1) * 4);
    int*   csrc     = (int*)  alloc((size_t)ET * 4);
    float* x1gat    = (float*)alloc((size_t)NN * 128 * 4);
    float* cat1     = (float*)alloc((size_t)NN * 128 * 4);
    float* x2gat    = (float*)alloc((size_t)NN * 128 * 4);
    float* skippre  = (float*)alloc((size_t)NN * 64 * 4);

    hipMemsetAsync(deg, 0, (size_t)2 * NN * 4, stream);
    hipMemsetAsync(x1gcnb, 0, (size_t)MPAD * 128 * 2, stream);  // pad rows interleaved

    const int MB = (NN + 63) / 64;

    // merged conversions + degree count
    conv_kernel<<<NBX + WBLK + EB, 256, 0, stream>>>(
        x, xb, W_gat1, W_skip, W_gat2, wt, w2t, ei, deg);

    // CSR by dst
    scan_kernel   <<<1, 256, 0, stream>>>(deg, rowst, dinv);
    scatter_kernel<<<EB, 256, 0, stream>>>(ei, rowst, cursor, csrc);

    // h1 (bf16) + skippre + fused alpha1, XCD-swizzled 64x128 BK=64, 4 waves
    mfma_gemm1_kernel<<<1120, 256, 0, stream>>>(xb, wt, a_src1, a_dst1,
                                                h1b, skippre, asrc, adst);

    // ---- GAT layer 1 (H=6) ----
    gat_agg_kernel<6><<<NN, 256, 0, stream>>>(h1b, asrc, adst, rowst, csrc,
                                              b_gat1, g1, be1, x1gat);
    // ---- GCN layer 1 (fp32 GEMM -> bf16 y) ----
    gemm_kernel<false, false, __bf16><<<dim3(2, MB), 256, 0, stream>>>(
        x1gat, 128, W_gcn1, 128, ybufb, 128, nullptr, NN, 128, 128);
    gcn_agg_kernel<<<NN, 128, 0, stream>>>(ybufb, 128, dinv, rowst, csrc,
                                           b_gcn1, cat1, 128, 0, x1gcnb);
    // ---- GAT layer 2 (H=4): h2 + fused alpha2 (bf16 MFMA, 4 waves) ----
    mfma_gemm2_kernel<<<dim3(4, MPAD / 64), 256, 0, stream>>>(
        x1gcnb, w2t, a_src2, a_dst2, h2b, asrc, adst);
    gat_agg_kernel<4><<<NN, 256, 0, stream>>>(h2b, asrc, adst, rowst, csrc,
                                              b_gat2, g2, be2, x2gat);
    // ---- GCN layer 2 GEMM (fp32 -> bf16 y2); aggregation fused into final ----
    gemm_kernel<false, false, __bf16><<<dim3(1, MB), 256, 0, stream>>>(
        x2gat, 128, W_gcn2, 64, ybufb, 64, nullptr, NN, 64, 128);
    // ---- GCN2 agg + fuse + LN + MLP (merged) ----
    fuse_final_kernel<<<(NN + 3) / 4, 256, 0, stream>>>(
        cat1, ybufb, dinv, rowst, csrc, b_gcn2,
        skippre, W_fuse, b_fuse, b_skip, g3, be3,
        W_c1, b_c1, W_c2, b_c2, W_c3, b_c3, out);
}

// Round 12
// 467.141 us; speedup vs baseline: 1.1182x; 1.1179x over previous
//
#include <hip/hip_runtime.h>
#include <cstdint>
#include <cstddef>

#define NN 10000
#define NE 160000
#define ET (NE + NN)          // edges + self loops
#define FIN 2000
#define MPAD 10112            // 158 * 64
#define KPAD 2048
#define NPAD 896              // 7 * 128 (768 gat1 cols + 64 skip + 64 pad)

typedef __bf16 bf16x8 __attribute__((ext_vector_type(8)));
typedef __bf16 bf16x4 __attribute__((ext_vector_type(4)));
typedef float  f32x4  __attribute__((ext_vector_type(4)));

#define GLL(src, dst) __builtin_amdgcn_global_load_lds( \
    (const __attribute__((address_space(1))) void*)(src), \
    (__attribute__((address_space(3))) void*)(dst), 16, 0, 0)

// ---------------------------------------------------------------------------
// CSR build
// ---------------------------------------------------------------------------
__device__ __forceinline__ void edge_sd(const int* ei, int e, int& s, int& d) {
    if (e < NE) { s = ei[e]; d = ei[NE + e]; }
    else        { s = e - NE; d = e - NE; }
}

// exclusive scan over deg -> rowstart[0..NN]; also dinv = deg^-1/2
__global__ void scan_kernel(const int* deg, int* rowstart, float* dinv) {
    __shared__ int partial[256];
    const int T = 256;
    int chunk = (NN + T - 1) / T;
    int t = threadIdx.x;
    int begin = t * chunk;
    int end = begin + chunk; if (end > NN) end = NN;
    int s = 0;
    for (int i = begin; i < end && i >= begin; i++) s += deg[i];
    partial[t] = s;
    __syncthreads();
    if (t == 0) {
        int run = 0;
        for (int i = 0; i < T; i++) { int v = partial[i]; partial[i] = run; run += v; }
    }
    __syncthreads();
    int run = partial[t];
    for (int i = begin; i < end && i >= begin; i++) {
        rowstart[i] = run; run += deg[i];
        int dg = deg[i];
        dinv[i] = dg > 0 ? rsqrtf((float)dg) : 0.f;
    }
    if (end == NN && begin <= NN) rowstart[NN] = run;
}

__global__ void scatter_kernel(const int* ei, const int* rowstart, int* cursor,
                               int* csr_src) {
    int e = blockIdx.x * blockDim.x + threadIdx.x;
    if (e >= ET) return;
    int s, d; edge_sd(ei, e, s, d);
    int pos = atomicAdd(&cursor[d], 1);
    csr_src[rowstart[d] + pos] = s;
}

// ---------------------------------------------------------------------------
// Merged conversion + degree count.
// Blocks [0, NBX): xb slab transpose via LDS (coalesced read AND write).
// Blocks [NBX, NBX+WBLK): wt / w2t / wgcn1s / wgcn2s conversion.
// Blocks [NBX+WBLK, ...): edge degree count (atomicAdd into deg).
// xb chunk c = ((rt*32 + ks)*8 + p)*64 + r holds x[rt*64+r][ks*64+p*8 ..+8)
// wt chunk: ((ct*32 + ks)*8 + p)*128 + r ; w2t chunk: (ct*16 + p)*128 + r
// wgcn1s chunk: p*128 + r (p 0..15) ; wgcn2s chunk: p*64 + r (p 0..15)
// ---------------------------------------------------------------------------
#define NBX (158 * 32)
#define NW1 (NPAD * KPAD / 8)                 // 229376
#define NWT (NW1 + 512 * 128 / 8)             // 237568
#define NWT2 (NWT + 2048 + 1024)              // + wgcn1s + wgcn2s
#define WBLK ((NWT2 + 255) / 256)
#define EB 665                                 // ceil(ET/256)
__global__ void conv_kernel(const float* __restrict__ x, __bf16* __restrict__ xb,
                            const float* __restrict__ Wg, const float* __restrict__ Ws,
                            const float* __restrict__ W2,
                            const float* __restrict__ Wg1, const float* __restrict__ Wg2,
                            __bf16* __restrict__ wt, __bf16* __restrict__ w2t,
                            __bf16* __restrict__ wgcn1s, __bf16* __restrict__ wgcn2s,
                            const int* __restrict__ ei, int* __restrict__ deg) {
    __shared__ __bf16 slab[4096];   // 8 planes x 64 rows x 8 = output chunk layout
    int bid = blockIdx.x;
    int tid = threadIdx.x;
    if (bid < NBX) {
        int rt = bid >> 5, ks = bid & 31;
        int r = tid >> 2;                 // 0..63
        int row = rt * 64 + r;
        int c0 = (tid & 3) * 16;          // 0,16,32,48
        int kbase = ks * 64;
#pragma unroll
        for (int j = 0; j < 4; j++) {
            int kl = c0 + j * 4;          // local k, mult of 4
            int k = kbase + kl;
            bf16x4 o;
            if (row < NN && k + 3 < FIN) {
                float4 v = *(const float4*)(x + (size_t)row * FIN + k);
                o[0] = (__bf16)v.x; o[1] = (__bf16)v.y;
                o[2] = (__bf16)v.z; o[3] = (__bf16)v.w;
            } else {
                o[0] = o[1] = o[2] = o[3] = (__bf16)0.f;
            }
            int p = kl >> 3, off = kl & 7;
            *(bf16x4*)(slab + (p * 64 + r) * 8 + off) = o;
        }
        __syncthreads();
        size_t base = (size_t)(rt * 32 + ks) * 512;   // chunk index
#pragma unroll
        for (int i = 0; i < 2; i++) {
            int c = i * 256 + tid;
            *(bf16x8*)(xb + (base + c) * 8) = *(const bf16x8*)(slab + c * 8);
        }
    } else if (bid < NBX + WBLK) {
        int g = (bid - NBX) * 256 + tid;
        if (g < NW1) {
            int r = g & 127, p = (g >> 7) & 7, ks = (g >> 10) & 31, ct = g >> 15;
            int n = ct * 128 + r;
            int k0 = ks * 64 + p * 8;
            bf16x8 o;
#pragma unroll
            for (int j = 0; j < 8; j++) {
                int k = k0 + j;
                float v = 0.f;
                if (k < FIN) {
                    if (n < 768)      v = Wg[(size_t)k * 768 + n];
                    else if (n < 832) v = Ws[(size_t)k * 64 + (n - 768)];
                }
                o[j] = (__bf16)v;
            }
            *(bf16x8*)(wt + (size_t)g * 8) = o;
        } else if (g < NWT) {
            int g2 = g - NW1;
            int c = g2 & 2047;
            int ct = g2 >> 11;
            int p = c >> 7, r = c & 127;
            int n = ct * 128 + r;
            int k0 = p * 8;
            bf16x8 o;
#pragma unroll
            for (int j = 0; j < 8; j++)
                o[j] = (__bf16)W2[(size_t)(k0 + j) * 512 + n];
            *(bf16x8*)(w2t + (size_t)g2 * 8) = o;
        } else if (g < NWT + 2048) {
            int g3 = g - NWT;
            int p = g3 >> 7, r = g3 & 127;
            bf16x8 o;
#pragma unroll
            for (int j = 0; j < 8; j++)
                o[j] = (__bf16)Wg1[(size_t)(p * 8 + j) * 128 + r];
            *(bf16x8*)(wgcn1s + (size_t)g3 * 8) = o;
        } else if (g < NWT2) {
            int g4 = g - NWT - 2048;
            int p = g4 >> 6, r = g4 & 63;
            bf16x8 o;
#pragma unroll
            for (int j = 0; j < 8; j++)
                o[j] = (__bf16)Wg2[(size_t)(p * 8 + j) * 64 + r];
            *(bf16x8*)(wgcn2s + (size_t)g4 * 8) = o;
        }
    } else {
        int e = (bid - NBX - WBLK) * 256 + tid;
        if (e < ET) {
            int s, d; edge_sd(ei, e, s, d);
            atomicAdd(&deg[d], 1);
        }
    }
}

// ---------------------------------------------------------------------------
// MFMA GEMM 1: xb @ wt^T -> h1b bf16[NN,768], skippre f32[NN,64], + fused
// alpha1. 64M x 128N block, 4 waves (32x64 each, 2x2), BK=64. 256 threads.
// (verified plateau shape: VGPR ~60, 4480 waves)
// ---------------------------------------------------------------------------
__global__ __launch_bounds__(256)
void mfma_gemm1_kernel(const __bf16* __restrict__ xb, const __bf16* __restrict__ wt,
                       const float* __restrict__ a_src1, const float* __restrict__ a_dst1,
                       __bf16* __restrict__ h1b, float* __restrict__ skippre,
                       float* __restrict__ asrc, float* __restrict__ adst) {
    __shared__ __bf16 As[4096];    // 8 planes x 64 rows x 8  (8 KB)
    __shared__ __bf16 Bs[8192];    // 8 planes x 128 rows x 8 (16 KB)
    __shared__ float sA[64], sD[64];
    __shared__ float asd[256];
    int b = blockIdx.x;
    int xcd = b & 7, j = b >> 3;
    int jq = j / 7;
    int rt = xcd + 8 * jq;
    int ct = j - 7 * jq;
    if (rt >= MPAD / 64) return;
    const int bi = rt * 64;
    const int bn = ct * 128;

    const int tid = threadIdx.x;
    const int lane = tid & 63;
    const int w = tid >> 6;
    const int wm = w >> 1, wn = w & 1;
    const int q = lane >> 4, m16 = lane & 15;

    if (tid < 64) { sA[tid] = 0.f; sD[tid] = 0.f; }
    if (ct < 6) {
        if (tid < 128) asd[tid] = a_src1[ct * 128 + tid];
        else           asd[tid] = a_dst1[ct * 128 + (tid - 128)];
    }

    f32x4 acc[2][4] = {};

    for (int ks = 0; ks < KPAD / 64; ks++) {
        const size_t slabA = (size_t)(rt * 32 + ks) * 512;
        const size_t slabB = (size_t)(ct * 32 + ks) * 1024;
#pragma unroll
        for (int i = 0; i < 2; i++) {
            int seg = i * 4 + w;
            GLL(xb + (slabA + seg * 64 + lane) * 8, As + seg * 512);
        }
#pragma unroll
        for (int i = 0; i < 4; i++) {
            int seg = i * 4 + w;
            GLL(wt + (slabB + seg * 64 + lane) * 8, Bs + seg * 512);
        }
        __syncthreads();

#pragma unroll
        for (int kk = 0; kk < 2; kk++) {
            const int pb = kk * 4 + q;
            bf16x8 af[2], bfr[4];
#pragma unroll
            for (int mt = 0; mt < 2; mt++)
                af[mt] = *(const bf16x8*)(As + (pb * 64 + wm * 32 + mt * 16 + m16) * 8);
#pragma unroll
            for (int nt = 0; nt < 4; nt++)
                bfr[nt] = *(const bf16x8*)(Bs + (pb * 128 + wn * 64 + nt * 16 + m16) * 8);
#pragma unroll
            for (int mt = 0; mt < 2; mt++)
#pragma unroll
                for (int nt = 0; nt < 4; nt++)
                    acc[mt][nt] = __builtin_amdgcn_mfma_f32_16x16x32_bf16(af[mt], bfr[nt], acc[mt][nt], 0, 0, 0);
        }
        __syncthreads();
    }

#pragma unroll
    for (int mt = 0; mt < 2; mt++) {
#pragma unroll
        for (int r = 0; r < 4; r++) {
            int rowl = wm * 32 + mt * 16 + q * 4 + r;
            int row = bi + rowl;
            float ps = 0.f, pd = 0.f;
#pragma unroll
            for (int nt = 0; nt < 4; nt++) {
                int coll = wn * 64 + nt * 16 + m16;
                int col = bn + coll;
                float v = acc[mt][nt][r];
                if (ct < 6) { ps += v * asd[coll]; pd += v * asd[128 + coll]; }
                if (row < NN) {
                    if (col < 768)      h1b[(size_t)row * 768 + col] = (__bf16)v;
                    else if (col < 832) skippre[(size_t)row * 64 + (col - 768)] = v;
                }
            }
            if (ct < 6) {
#pragma unroll
                for (int off = 1; off < 16; off <<= 1) {
                    ps += __shfl_xor(ps, off);
                    pd += __shfl_xor(pd, off);
                }
                if (m16 == 0) { atomicAdd(&sA[rowl], ps); atomicAdd(&sD[rowl], pd); }
            }
        }
    }
    if (ct < 6) {
        __syncthreads();
        if (tid < 64) {
            int row = bi + tid;
            if (row < NN) { asrc[row * 6 + ct] = sA[tid]; adst[row * 6 + ct] = sD[tid]; }
        }
    }
}

// ---------------------------------------------------------------------------
// MFMA GEMM 2: x1gcnb(swizzled)[MPAD,128] @ w2t(swizzled)[512,128]^T -> h2b
// bf16[NN,512], + fused alpha2. 64x128 block, 4 waves (32x64), BK=64, 256 thr.
// ---------------------------------------------------------------------------
__global__ __launch_bounds__(256)
void mfma_gemm2_kernel(const __bf16* __restrict__ A, const __bf16* __restrict__ B,
                       const float* __restrict__ a_src2, const float* __restrict__ a_dst2,
                       __bf16* __restrict__ h2b,
                       float* __restrict__ asrc, float* __restrict__ adst) {
    __shared__ __bf16 As[4096];
    __shared__ __bf16 Bs[8192];
    __shared__ float sA[64], sD[64];
    __shared__ float asd[256];
    const int rt = blockIdx.y, ct = blockIdx.x;
    const int bi = rt * 64, bn = ct * 128;
    const int tid = threadIdx.x, lane = tid & 63, w = tid >> 6;
    const int wm = w >> 1, wn = w & 1;
    const int q = lane >> 4, m16 = lane & 15;

    if (tid < 64) { sA[tid] = 0.f; sD[tid] = 0.f; }
    if (tid < 128) asd[tid] = a_src2[ct * 128 + tid];
    else           asd[tid] = a_dst2[ct * 128 + (tid - 128)];

    f32x4 acc[2][4] = {};

    for (int ks = 0; ks < 2; ks++) {
        const size_t slabA = (size_t)rt * 1024 + ks * 512;
        const size_t slabB = (size_t)ct * 2048 + ks * 1024;
#pragma unroll
        for (int i = 0; i < 2; i++) {
            int seg = i * 4 + w;
            GLL(A + (slabA + seg * 64 + lane) * 8, As + seg * 512);
        }
#pragma unroll
        for (int i = 0; i < 4; i++) {
            int seg = i * 4 + w;
            GLL(B + (slabB + seg * 64 + lane) * 8, Bs + seg * 512);
        }
        __syncthreads();

#pragma unroll
        for (int kk = 0; kk < 2; kk++) {
            const int pb = kk * 4 + q;
            bf16x8 af[2], bfr[4];
#pragma unroll
            for (int mt = 0; mt < 2; mt++)
                af[mt] = *(const bf16x8*)(As + (pb * 64 + wm * 32 + mt * 16 + m16) * 8);
#pragma unroll
            for (int nt = 0; nt < 4; nt++)
                bfr[nt] = *(const bf16x8*)(Bs + (pb * 128 + wn * 64 + nt * 16 + m16) * 8);
#pragma unroll
            for (int mt = 0; mt < 2; mt++)
#pragma unroll
                for (int nt = 0; nt < 4; nt++)
                    acc[mt][nt] = __builtin_amdgcn_mfma_f32_16x16x32_bf16(af[mt], bfr[nt], acc[mt][nt], 0, 0, 0);
        }
        __syncthreads();
    }

#pragma unroll
    for (int mt = 0; mt < 2; mt++) {
#pragma unroll
        for (int r = 0; r < 4; r++) {
            int rowl = wm * 32 + mt * 16 + q * 4 + r;
            int row = bi + rowl;
            float ps = 0.f, pd = 0.f;
#pragma unroll
            for (int nt = 0; nt < 4; nt++) {
                int coll = wn * 64 + nt * 16 + m16;
                float v = acc[mt][nt][r];
                ps += v * asd[coll]; pd += v * asd[128 + coll];
                if (row < NN) h2b[(size_t)row * 512 + bn + coll] = (__bf16)v;
            }
#pragma unroll
            for (int off = 1; off < 16; off <<= 1) {
                ps += __shfl_xor(ps, off);
                pd += __shfl_xor(pd, off);
            }
            if (m16 == 0) { atomicAdd(&sA[rowl], ps); atomicAdd(&sD[rowl], pd); }
        }
    }
    __syncthreads();
    if (tid < 64) {
        int row = bi + tid;
        if (row < NN) { asrc[row * 4 + ct] = sA[tid]; adst[row * 4 + ct] = sD[tid]; }
    }
}

// ---------------------------------------------------------------------------
// MFMA GCN GEMM: A(swizzled)[MPAD,128] @ Bs(swizzled)[NT,128]^T -> y bf16[NN,NT]
// 64M x NT block, 4 waves, BK=64 (2 iters), 256 threads. NT in {64,128}.
// NT=128: waves 2x2 (32x64 tiles). NT=64: waves stacked (16x64 tiles).
// ---------------------------------------------------------------------------
template<int NT>
__global__ __launch_bounds__(256)
void mfma_gcn_kernel(const __bf16* __restrict__ A, const __bf16* __restrict__ B,
                     __bf16* __restrict__ Cb) {
    __shared__ __bf16 As[4096];
    __shared__ __bf16 Bs[NT * 64];      // 8 planes x NT rows x 8
    const int rt = blockIdx.x;
    const int bi = rt * 64;
    const int tid = threadIdx.x, lane = tid & 63, w = tid >> 6;
    const int q = lane >> 4, m16 = lane & 15;
    constexpr int MT = (NT == 128) ? 2 : 1;
    constexpr int MSPAN = (NT == 128) ? 32 : 16;
    const int wm = (NT == 128) ? (w >> 1) : w;
    const int wn = (NT == 128) ? (w & 1) : 0;

    f32x4 acc[MT][4] = {};

    for (int ks = 0; ks < 2; ks++) {
        const size_t slabA = (size_t)rt * 1024 + ks * 512;
        const size_t slabB = (size_t)ks * (NT * 8);
#pragma unroll
        for (int i = 0; i < 2; i++) {
            int seg = i * 4 + w;
            GLL(A + (slabA + seg * 64 + lane) * 8, As + seg * 512);
        }
#pragma unroll
        for (int i = 0; i < NT / 32; i++) {
            int seg = i * 4 + w;
            GLL(B + (slabB + (size_t)seg * 64 + lane) * 8, Bs + seg * 512);
        }
        __syncthreads();

#pragma unroll
        for (int kk = 0; kk < 2; kk++) {
            const int pb = kk * 4 + q;
            bf16x8 af[MT], bfr[4];
#pragma unroll
            for (int mt = 0; mt < MT; mt++)
                af[mt] = *(const bf16x8*)(As + (pb * 64 + wm * MSPAN + mt * 16 + m16) * 8);
#pragma unroll
            for (int nt = 0; nt < 4; nt++)
                bfr[nt] = *(const bf16x8*)(Bs + (pb * NT + wn * 64 + nt * 16 + m16) * 8);
#pragma unroll
            for (int mt = 0; mt < MT; mt++)
#pragma unroll
                for (int nt = 0; nt < 4; nt++)
                    acc[mt][nt] = __builtin_amdgcn_mfma_f32_16x16x32_bf16(af[mt], bfr[nt], acc[mt][nt], 0, 0, 0);
        }
        __syncthreads();
    }

#pragma unroll
    for (int mt = 0; mt < MT; mt++) {
#pragma unroll
        for (int r = 0; r < 4; r++) {
            int row = bi + wm * MSPAN + mt * 16 + q * 4 + r;
            if (row >= NN) continue;
#pragma unroll
            for (int nt = 0; nt < 4; nt++) {
                int col = wn * 64 + nt * 16 + m16;
                Cb[(size_t)row * NT + col] = (__bf16)acc[mt][nt][r];
            }
        }
    }
}

// ---------------------------------------------------------------------------
// Fused segment-softmax + aggregation + head-mean + bias + LN + ReLU.
// Phase 1 caches src ids + exp values in LDS (CAP edges). Output is bf16 in
// the MFMA-A swizzled layout (consumed by mfma_gcn).
// ---------------------------------------------------------------------------
template<int H>
__global__ void gat_agg_kernel(const __bf16* __restrict__ hb,
                               const float* __restrict__ asrc,
                               const float* __restrict__ adst,
                               const int* __restrict__ rowstart,
                               const int* __restrict__ csr_src,
                               const float* __restrict__ bias,
                               const float* __restrict__ gamma,
                               const float* __restrict__ beta,
                               __bf16* __restrict__ outs) {
    constexpr int CH = H * 128;
    constexpr int CAP = 128;
    int n = blockIdx.x;
    int t = threadIdx.x;
    int w = t >> 6, l = t & 63;
    __shared__ float invden[H];
    __shared__ float denw[4][H];
    __shared__ int   srcs[CAP];
    __shared__ float evs[CAP * H];
    __shared__ float sm[4 * CH];
    __shared__ float red[8];

    int s0 = rowstart[n];
    int deg = rowstart[n + 1] - s0;
    float adst_n = (l < H) ? adst[n * H + l] : 0.f;

    // phase 1: denominators + cache src/ev
    float dloc = 0.f;
    for (int idx = w; idx < deg; idx += 4) {
        int src = csr_src[s0 + idx];
        if (idx < CAP && l == 0) srcs[idx] = src;
        if (l < H) {
            float al = asrc[src * H + l] + adst_n;
            al = al >= 0.f ? al : 0.2f * al;
            float ev = __expf(al);
            dloc += ev;
            if (idx < CAP) evs[idx * H + l] = ev;
        }
    }
    if (l < H) denw[w][l] = dloc;
    __syncthreads();
    if (t < H) invden[t] = 1.f / (denw[0][t] + denw[1][t] + denw[2][t] + denw[3][t]);
    __syncthreads();

    // phase 2: weighted feature accumulation from cached LDS, 2-edge pipelined
    constexpr int NA = (H == 6) ? 12 : 8;
    float acc[NA] = {};
    const int h0 = l >> 4;
    const int h1i = 4 + (l >> 5);
    int degc = deg < CAP ? deg : CAP;
    int idx = w;
    for (; idx + 4 < degc; idx += 8) {
        int src0 = srcs[idx], src1 = srcs[idx + 4];
        float w00 = evs[idx * H + h0];
        float w10 = evs[(idx + 4) * H + h0];
        const __bf16* hp0 = hb + (size_t)src0 * CH;
        const __bf16* hp1 = hb + (size_t)src1 * CH;
        bf16x8 g00 = *(const bf16x8*)(hp0 + l * 8);
        bf16x8 g10 = *(const bf16x8*)(hp1 + l * 8);
#pragma unroll
        for (int jj = 0; jj < 8; jj++)
            acc[jj] += (float)g00[jj] * w00 + (float)g10[jj] * w10;
        if (H == 6) {
            float w01 = evs[idx * H + h1i];
            float w11 = evs[(idx + 4) * H + h1i];
            bf16x4 g01 = *(const bf16x4*)(hp0 + 512 + l * 4);
            bf16x4 g11 = *(const bf16x4*)(hp1 + 512 + l * 4);
#pragma unroll
            for (int jj = 0; jj < 4; jj++)
                acc[8 + jj] += (float)g01[jj] * w01 + (float)g11[jj] * w11;
        }
    }
    if (idx < degc) {
        int src = srcs[idx];
        float w0 = evs[idx * H + h0];
        const __bf16* hp = hb + (size_t)src * CH;
        bf16x8 hv = *(const bf16x8*)(hp + l * 8);
#pragma unroll
        for (int jj = 0; jj < 8; jj++) acc[jj] += (float)hv[jj] * w0;
        if (H == 6) {
            float w1 = evs[idx * H + h1i];
            bf16x4 hv1 = *(const bf16x4*)(hp + 512 + l * 4);
#pragma unroll
            for (int jj = 0; jj < 4; jj++) acc[8 + jj] += (float)hv1[jj] * w1;
        }
    }
    // fallback: uncached edges (deg > CAP; effectively never for this graph)
    for (int i2 = CAP + w; i2 < deg; i2 += 4) {
        int src = csr_src[s0 + i2];
        float ev = 0.f;
        if (l < H) {
            float al = asrc[src * H + l] + adst_n;
            al = al >= 0.f ? al : 0.2f * al;
            ev = __expf(al);
        }
        const __bf16* hp = hb + (size_t)src * CH;
        float wgt = __shfl(ev, h0);
        bf16x8 hv = *(const bf16x8*)(hp + l * 8);
#pragma unroll
        for (int jj = 0; jj < 8; jj++) acc[jj] += (float)hv[jj] * wgt;
        if (H == 6) {
            float wg1 = __shfl(ev, h1i);
            bf16x4 hv1 = *(const bf16x4*)(hp + 512 + l * 4);
#pragma unroll
            for (int jj = 0; jj < 4; jj++) acc[8 + jj] += (float)hv1[jj] * wg1;
        }
    }

    *(f32x4*)(sm + w * CH + l * 8)     = *(f32x4*)(acc);
    *(f32x4*)(sm + w * CH + l * 8 + 4) = *(f32x4*)(acc + 4);
    if (H == 6)
        *(f32x4*)(sm + w * CH + 512 + l * 4) = *(f32x4*)(acc + 8);
    __syncthreads();

    float v = 0.f;
    if (t < 128) {
#pragma unroll
        for (int hh = 0; hh < H; hh++) {
            float hsum = 0.f;
#pragma unroll
            for (int ww = 0; ww < 4; ww++) hsum += sm[ww * CH + hh * 128 + t];
            v += hsum * invden[hh];
        }
        v = v * (1.f / H) + bias[t];
    }
    float sv = (t < 128) ? v : 0.f;
    float sq = (t < 128) ? v * v : 0.f;
#pragma unroll
    for (int off = 32; off; off >>= 1) {
        sv += __shfl_down(sv, off);
        sq += __shfl_down(sq, off);
    }
    if ((t & 63) == 0) { red[w * 2] = sv; red[w * 2 + 1] = sq; }
    __syncthreads();
    float tot = red[0] + red[2] + red[4] + red[6];
    float tsq = red[1] + red[3] + red[5] + red[7];
    float mu = tot * (1.f / 128.f);
    float var = tsq * (1.f / 128.f) - mu * mu;
    float r = rsqrtf(var + 1e-5f);
    if (t < 128) {
        float o = fmaxf((v - mu) * r * gamma[t] + beta[t], 0.f);
        // MFMA-A swizzled store: n -> (rt,r), t -> (p,off)
        int rt2 = n >> 6, rr = n & 63, pp = t >> 3, off2 = t & 7;
        outs[((size_t)(rt2 * 16 + pp) * 64 + rr) * 8 + off2] = (__bf16)o;
    }
}

// per-node GCN aggregation from bf16 y; fp32 out slice + optional swizzled bf16
__global__ void gcn_agg_kernel(const __bf16* __restrict__ y, int C,
                               const float* __restrict__ dinv,
                               const int* __restrict__ rowstart,
                               const int* __restrict__ csr_src,
                               const float* __restrict__ bias,
                               float* __restrict__ out, int ldo, int coloff,
                               __bf16* __restrict__ bout) {
    int n = blockIdx.x;
    int t = threadIdx.x;  // blockDim == C
    float acc = 0.f;
    int s0 = rowstart[n], s1 = rowstart[n + 1];
    for (int s = s0; s < s1; s++) {
        int src = csr_src[s];
        acc += (float)y[(size_t)src * C + t] * dinv[src];
    }
    float v = fmaxf(acc * dinv[n] + bias[t], 0.f);
    out[(size_t)n * ldo + coloff + t] = v;
    if (bout) {
        // swizzled layout for mfma_gemm2: idx = ((rt*16 + p)*64 + r)*8 + off
        int rt = n >> 6, r = n & 63, p = t >> 3, off = t & 7;
        bout[((size_t)(rt * 16 + p) * 64 + r) * 8 + off] = (__bf16)v;
    }
}

// ---------------------------------------------------------------------------
// Fused: fused=relu(cat@W_fuse+b_fuse); v=fused+relu(skippre+b_skip);
// LN(v) -> 64->32->16->5 MLP. 4 nodes/block (one per wave), W_fuse in LDS.
// (round-9 verified version)
// ---------------------------------------------------------------------------
__global__ __launch_bounds__(256)
void fuse_final_kernel(const float* __restrict__ cat,
                       const float* __restrict__ skippre,
                       const float* __restrict__ Wf, const float* __restrict__ bfz,
                       const float* __restrict__ b_skip,
                       const float* __restrict__ g3, const float* __restrict__ be3,
                       const float* __restrict__ Wc1, const float* __restrict__ bc1,
                       const float* __restrict__ Wc2, const float* __restrict__ bc2,
                       const float* __restrict__ Wc3, const float* __restrict__ bc3,
                       float* __restrict__ out) {
    __shared__ float WfS[192 * 64];     // 48 KB
    __shared__ float catS[4][196];
    __shared__ float fS[4][64], h1S[4][32], h2S[4][16];
    int tid = threadIdx.x;
    int w = tid >> 6, l = tid & 63;
#pragma unroll
    for (int i = 0; i < 12; i++) {
        int idx = (i * 256 + tid) * 4;
        *(f32x4*)(WfS + idx) = *(const f32x4*)(Wf + idx);
    }
    int n = blockIdx.x * 4 + w;
    bool act = n < NN;
    float sk = 0.f;
    if (act) {
        catS[w][l]       = cat[(size_t)n * 192 + l];
        catS[w][64 + l]  = cat[(size_t)n * 192 + 64 + l];
        catS[w][128 + l] = cat[(size_t)n * 192 + 128 + l];
        sk = fmaxf(skippre[(size_t)n * 64 + l] + b_skip[l], 0.f);
    }
    __syncthreads();

    float fu = bfz[l];
#pragma unroll 4
    for (int k = 0; k < 192; k++)
        fu += catS[w][k] * WfS[k * 64 + l];
    float v = fmaxf(fu, 0.f) + sk;

    float sv = v, sq = v * v;
#pragma unroll
    for (int off = 32; off; off >>= 1) {
        sv += __shfl_xor(sv, off);
        sq += __shfl_xor(sq, off);
    }
    float mu = sv * (1.f / 64.f);
    float var = sq * (1.f / 64.f) - mu * mu;
    float r = rsqrtf(var + 1e-5f);
    fS[w][l] = (v - mu) * r * g3[l] + be3[l];
    __syncthreads();
    if (l < 32) {
        float a = bc1[l];
        for (int i = 0; i < 64; i++) a += fS[w][i] * Wc1[i * 32 + l];
        h1S[w][l] = fmaxf(a, 0.f);
    }
    __syncthreads();
    if (l < 16) {
        float a = bc2[l];
        for (int i = 0; i < 32; i++) a += h1S[w][i] * Wc2[i * 16 + l];
        h2S[w][l] = fmaxf(a, 0.f);
    }
    __syncthreads();
    if (l < 5 && act) {
        float a = bc3[l];
        for (int i = 0; i < 16; i++) a += h2S[w][i] * Wc3[i * 5 + l];
        out[(size_t)n * 5 + l] = a;
    }
}

// ---------------------------------------------------------------------------
extern "C" void kernel_launch(void* const* d_in, const int* in_sizes, int n_in,
                              void* d_out, int out_size, void* d_ws, size_t ws_size,
                              hipStream_t stream) {
    const float* x      = (const float*)d_in[0];
    const int*   ei     = (const int*)d_in[1];
    const float* W_gat1 = (const float*)d_in[2];
    const float* a_src1 = (const float*)d_in[3];
    const float* a_dst1 = (const float*)d_in[4];
    const float* b_gat1 = (const float*)d_in[5];
    const float* W_gcn1 = (const float*)d_in[6];
    const float* b_gcn1 = (const float*)d_in[7];
    const float* W_gat2 = (const float*)d_in[8];
    const float* a_src2 = (const float*)d_in[9];
    const float* a_dst2 = (const float*)d_in[10];
    const float* b_gat2 = (const float*)d_in[11];
    const float* W_gcn2 = (const float*)d_in[12];
    const float* b_gcn2 = (const float*)d_in[13];
    const float* W_skip = (const float*)d_in[14];
    const float* b_skip = (const float*)d_in[15];
    const float* W_fuse = (const float*)d_in[16];
    const float* b_fuse = (const float*)d_in[17];
    const float* W_c1   = (const float*)d_in[18];
    const float* b_c1   = (const float*)d_in[19];
    const float* W_c2   = (const float*)d_in[20];
    const float* b_c2   = (const float*)d_in[21];
    const float* W_c3   = (const float*)d_in[22];
    const float* b_c3   = (const float*)d_in[23];
    const float* g1     = (const float*)d_in[24];
    const float* be1    = (const float*)d_in[25];
    const float* g2     = (const float*)d_in[26];
    const float* be2    = (const float*)d_in[27];
    const float* g3     = (const float*)d_in[28];
    const float* be3    = (const float*)d_in[29];
    float* out = (float*)d_out;

    // workspace arena
    char* p = (char*)d_ws;
    auto alloc = [&](size_t bytes) {
        char* r = p; p += (bytes + 255) & ~(size_t)255; return r;
    };
    __bf16* xb      = (__bf16*)alloc((size_t)MPAD * KPAD * 2);   // 41.4 MB (swizzled)
    __bf16* wt      = (__bf16*)alloc((size_t)NPAD * KPAD * 2);   // 3.7 MB  (swizzled)
    __bf16* w2t     = (__bf16*)alloc((size_t)512 * 128 * 2);     // swizzled
    __bf16* wgcn1s  = (__bf16*)alloc((size_t)128 * 128 * 2);     // swizzled
    __bf16* wgcn2s  = (__bf16*)alloc((size_t)64 * 128 * 2);      // swizzled
    __bf16* h1b     = (__bf16*)alloc((size_t)NN * 768 * 2);      // 15.4 MB
    __bf16* h2b     = (__bf16*)alloc((size_t)NN * 512 * 2);      // 10.2 MB
    __bf16* ybufb   = (__bf16*)alloc((size_t)NN * 128 * 2);      // y1 reused y2
    // three swizzled activation buffers, contiguous for a single memset
    __bf16* x1gatb  = (__bf16*)alloc((size_t)3 * MPAD * 128 * 2);
    __bf16* x1gcnb  = x1gatb + (size_t)MPAD * 128;
    __bf16* x2gatb  = x1gcnb + (size_t)MPAD * 128;
    float* asrc     = (float*)alloc((size_t)NN * 6 * 4);
    float* adst     = (float*)alloc((size_t)NN * 6 * 4);
    int*   deg      = (int*)  alloc((size_t)2 * NN * 4);         // deg | cursor
    int*   cursor   = deg + NN;
    float* dinv     = (float*)alloc((size_t)NN * 4);
    int*   rowst    = (int*)  alloc((size_t)(NN + 1) * 4);
    int*   csrc     = (int*)  alloc((size_t)ET * 4);
    float* cat      = (float*)alloc((size_t)NN * 192 * 4);
    float* skippre  = (float*)alloc((size_t)NN * 64 * 4);

    hipMemsetAsync(deg, 0, (size_t)2 * NN * 4, stream);
    hipMemsetAsync(x1gatb, 0, (size_t)3 * MPAD * 128 * 2, stream);  // pad rows

    // merged conversions + degree count
    conv_kernel<<<NBX + WBLK + EB, 256, 0, stream>>>(
        x, xb, W_gat1, W_skip, W_gat2, W_gcn1, W_gcn2,
        wt, w2t, wgcn1s, wgcn2s, ei, deg);

    // CSR by dst
    scan_kernel   <<<1, 256, 0, stream>>>(deg, rowst, dinv);
    scatter_kernel<<<EB, 256, 0, stream>>>(ei, rowst, cursor, csrc);

    // h1 (bf16) + skippre + fused alpha1, XCD-swizzled 64x128 BK=64, 4 waves
    mfma_gemm1_kernel<<<1120, 256, 0, stream>>>(xb, wt, a_src1, a_dst1,
                                                h1b, skippre, asrc, adst);

    // ---- GAT layer 1 (H=6) -> bf16 swizzled x1gatb ----
    gat_agg_kernel<6><<<NN, 256, 0, stream>>>(h1b, asrc, adst, rowst, csrc,
                                              b_gat1, g1, be1, x1gatb);
    // ---- GCN layer 1: y1 = x1gat @ W_gcn1 (MFMA) ----
    mfma_gcn_kernel<128><<<MPAD / 64, 256, 0, stream>>>(x1gatb, wgcn1s, ybufb);
    gcn_agg_kernel<<<NN, 128, 0, stream>>>(ybufb, 128, dinv, rowst, csrc,
                                           b_gcn1, cat, 192, 0, x1gcnb);
    // ---- GAT layer 2 (H=4): h2 + fused alpha2 (bf16 MFMA, 4 waves) ----
    mfma_gemm2_kernel<<<dim3(4, MPAD / 64), 256, 0, stream>>>(
        x1gcnb, w2t, a_src2, a_dst2, h2b, asrc, adst);
    gat_agg_kernel<4><<<NN, 256, 0, stream>>>(h2b, asrc, adst, rowst, csrc,
                                              b_gat2, g2, be2, x2gatb);
    // ---- GCN layer 2: y2 = x2gat @ W_gcn2 (MFMA) -> cat[:, 128:192] ----
    mfma_gcn_kernel<64><<<MPAD / 64, 256, 0, stream>>>(x2gatb, wgcn2s, ybufb);
    gcn_agg_kernel<<<NN, 64, 0, stream>>>(ybufb, 64, dinv, rowst, csrc,
                                          b_gcn2, cat, 192, 128, nullptr);
    // ---- fuse + final (merged, round-9 version) ----
    fuse_final_kernel<<<(NN + 3) / 4, 256, 0, stream>>>(
        cat, skippre, W_fuse, b_fuse, b_skip, g3, be3,
        W_c1, b_c1, W_c2, b_c2, W_c3, b_c3, out);
}